// Round 9
// baseline (272.504 us; speedup 1.0000x reference)
//
#include <hip/hip_runtime.h>
#include <hip/hip_bf16.h>
#include <math.h>

// Problem constants (HC2MMoE)
#define B_    16384
#define IN_   1024
#define E_    6
#define D_    20
#define EH1_  256
#define EH2_  128
#define EO_   10
#define GH_   64
#define TH_   64

typedef short  s16x8  __attribute__((ext_vector_type(8)));   // 8 bf16 = 4 VGPRs
typedef float  f32x4  __attribute__((ext_vector_type(4)));
typedef float  f32x16 __attribute__((ext_vector_type(16)));

__device__ inline ushort f2bf(float f) {   // RNE fp32 -> bf16 bits
    union { float f; uint32_t u; } v; v.f = f;
    return (ushort)((v.u + 0x7fffu + ((v.u >> 16) & 1u)) >> 16);
}

__device__ inline s16x8 cvt8(float4 a, float4 b) {
    s16x8 v;
    v[0] = f2bf(a.x); v[1] = f2bf(a.y); v[2] = f2bf(a.z); v[3] = f2bf(a.w);
    v[4] = f2bf(b.x); v[5] = f2bf(b.y); v[6] = f2bf(b.z); v[7] = f2bf(b.w);
    return v;
}

#define GLOBAL_LDS16(g, l)                                                     \
    __builtin_amdgcn_global_load_lds(                                          \
        (const __attribute__((address_space(1))) void*)(g),                    \
        (__attribute__((address_space(3))) void*)(l), 16, 0, 0)

#define NCHUNK (B_ / 256)   // 64

// ---------------------------------------------------------------------------
// Prep (R9): weight transposes + per-chunk domain counts ONLY. The x->bf16
// conversion pass is GONE: GEMM/gate stage A directly from fp32 with on-the-
// fly f2bf (identical RNE bits). Removes 96 MB (2/3) of prep traffic.
// ---------------------------------------------------------------------------
#define WT1_TILES ((EH1_ / 32) * (IN_ / 32) * E_)            // 1536
#define WT2_TILES ((EH2_ / 32) * (EH1_ / 32) * E_)           // 192
#define WTG_TILES ((GH_ / 32) * (IN_ / 32) * D_)             // 1280
#define PREP_BLKS (WT1_TILES + WT2_TILES + WTG_TILES + NCHUNK)

__global__ __launch_bounds__(256) void k_prep(
        const float* __restrict__ Ew1, ushort* __restrict__ W1t,
        const float* __restrict__ Ew2, ushort* __restrict__ W2t,
        const float* __restrict__ Gw1, ushort* __restrict__ G1t,
        const int* __restrict__ dom, int* __restrict__ cnts) {
    __shared__ float tile[32][33];
    __shared__ int hcnt[D_];
    int bid = blockIdx.x;
    const int t = threadIdx.x;

    const float* W; ushort* Wt; int K, N, z, ky, nx;
    if (bid < WT1_TILES) {
        W = Ew1; Wt = W1t; K = IN_; N = EH1_;
        z = bid / (8 * 32); int r = bid % (8 * 32); ky = r / 8; nx = r % 8;
    } else if (bid < WT1_TILES + WT2_TILES) {
        bid -= WT1_TILES;
        W = Ew2; Wt = W2t; K = EH1_; N = EH2_;
        z = bid / (4 * 8); int r = bid % (4 * 8); ky = r / 4; nx = r % 4;
    } else if (bid < WT1_TILES + WT2_TILES + WTG_TILES) {
        bid -= WT1_TILES + WT2_TILES;
        W = Gw1; Wt = G1t; K = IN_; N = GH_;
        z = bid / (2 * 32); int r = bid % (2 * 32); ky = r / 2; nx = r % 2;
    } else {
        // per-chunk count blocks: 256 samples each, LDS counts -> direct write
        int c = bid - (WT1_TILES + WT2_TILES + WTG_TILES);
        if (t < D_) hcnt[t] = 0;
        __syncthreads();
        atomicAdd(&hcnt[dom[c * 256 + t]], 1);
        __syncthreads();
        if (t < D_) cnts[c * D_ + t] = hcnt[t];
        return;
    }
    const int n0 = nx * 32, k0 = ky * 32;
    const float* We = W + (size_t)z * K * N;
    ushort* Wte = Wt + (size_t)z * K * N;
    const int lx = t & 31, ly = t >> 5;
    #pragma unroll
    for (int r = 0; r < 4; ++r)
        tile[ly + r * 8][lx] = We[(size_t)(k0 + ly + r * 8) * N + n0 + lx];
    __syncthreads();
    #pragma unroll
    for (int r = 0; r < 4; ++r)
        Wte[(size_t)(n0 + ly + r * 8) * K + k0 + lx] = f2bf(tile[lx][ly + r * 8]);
}

#define GBK 32
#define H2P 136

// ---------------------------------------------------------------------------
// L1 GEMM (R6-verified 128x128/BK=32/256t config — R8's 128x256 widening
// regressed 72.6->76.3 despite FETCH -27MB: the 2-barrier structure is the
// ceiling, not FETCH. A-staging now reads fp32 x directly: 2x float4 loads +
// f2bf + ds_write_b128 into the IDENTICAL swizzled LDS layout (fragment
// reads untouched). B stays on global_load_lds. Scatter prologue on 64
// resident blocks (R6-verified).
// ---------------------------------------------------------------------------
__global__ __launch_bounds__(256) void k_gemm(
        const float* __restrict__ X, const ushort* __restrict__ Wt,
        const float* __restrict__ Bias, ushort* __restrict__ C,
        const int* __restrict__ dom, const int* __restrict__ cnts,
        int* __restrict__ perm, int* __restrict__ gbaseG,
        int* __restrict__ histG, int* __restrict__ gtab,
        int* __restrict__ ngt) {
    __shared__ __attribute__((aligned(16))) ushort As[128 * GBK];
    __shared__ __attribute__((aligned(16))) ushort Bs[128 * GBK];

    const int t = threadIdx.x;

    if (blockIdx.z == 0 && blockIdx.x == 0 && blockIdx.y < NCHUNK) {
        // ---------- scatter prologue (LDS aliases As; done before staging) --
        int* cl    = (int*)As;              // [NCHUNK*D_] = 1280 ints (5120B)
        int* tot   = cl + NCHUNK * D_;      // [D_]
        int* lbase = tot + D_;              // [D_]
        int* lcnt  = lbase + D_;            // [D_]
        const int c = blockIdx.y;

        for (int i = t; i < NCHUNK * D_; i += 256) cl[i] = cnts[i];
        __syncthreads();
        if (t < D_) {
            int before = 0, total = 0;
            #pragma unroll 8
            for (int cc = 0; cc < NCHUNK; ++cc) {
                int v = cl[cc * D_ + t];
                if (cc < c) before += v;
                total += v;
            }
            tot[t] = total; lbase[t] = before; lcnt[t] = 0;
        }
        __syncthreads();
        if (t < D_) {
            int gb = 0;
            #pragma unroll
            for (int d2 = 0; d2 < D_; ++d2) if (d2 < t) gb += tot[d2];
            lbase[t] += gb;
            if (c == 0) { gbaseG[t] = gb; histG[t] = tot[t]; }
        }
        __syncthreads();
        if (c == 0 && t < D_) {
            // parallel gate-table build: thread t owns domain t's entries
            int off = 0, nt = (tot[t] + 63) >> 6;
            #pragma unroll
            for (int d2 = 0; d2 < D_; ++d2)
                if (d2 < t) off += (tot[d2] + 63) >> 6;
            for (int tt = 0; tt < nt; ++tt) gtab[off + tt] = (t << 16) | tt;
            if (t == D_ - 1) ngt[0] = off + nt;
        }
        {
            const int g = c * 256 + t;
            const int d = dom[g];
            int r = atomicAdd(&lcnt[d], 1);     // LDS-only rank within chunk
            perm[lbase[d] + r] = g;
        }
        __syncthreads();   // As safe to reuse for GEMM staging
    }

    // ---------------- expert L1 GEMM ----------------
    const int e = blockIdx.z;
    const ushort* We = Wt + (size_t)e * (size_t)EH1_ * IN_;
    const float* BiasE = Bias + (size_t)e * EH1_;
    ushort* Ce = C + (size_t)e * (size_t)B_ * EH1_;

    const int m0 = blockIdx.y * 128;
    const int n0 = blockIdx.x * 128;
    const int wave = t >> 6;
    const int lane = t & 63;

    const int q0 = wave * 2, q1 = q0 + 1;
    const int sr0 = q0 * 16 + (lane >> 2);
    const int sr1 = sr0 + 16;
    const int sw  = ((lane & 3) ^ ((sr0 >> 1) & 3)) * 8;

    const int l32  = lane & 31;
    const int ksel = lane >> 5;
    const int rw = (wave & 1) * 64;
    const int cw = (wave >> 1) * 64;

    int rowA[2], rowB[2], swzA[2], swzB[2];
    #pragma unroll
    for (int i = 0; i < 2; ++i) {
        rowA[i] = rw + 32 * i + l32;  swzA[i] = (rowA[i] >> 1) & 3;
        rowB[i] = cw + 32 * i + l32;  swzB[i] = (rowB[i] >> 1) & 3;
    }

    // fp32 A sources + LDS dests (layout identical to the old gload path:
    // dest elem = qx*512 + lane*8 holds row srx, cols [sw, sw+8))
    const float* xr0 = X + (size_t)(m0 + sr0) * IN_ + sw;
    const float* xr1 = X + (size_t)(m0 + sr1) * IN_ + sw;
    ushort* dst0 = As + q0 * 512 + lane * 8;
    ushort* dst1 = As + q1 * 512 + lane * 8;

    f32x16 acc[2][2] = {};

    for (int k0 = 0; k0 < IN_; k0 += GBK) {
        GLOBAL_LDS16(We + (size_t)(n0 + sr0) * IN_ + k0 + sw, Bs + q0 * 512);
        GLOBAL_LDS16(We + (size_t)(n0 + sr1) * IN_ + k0 + sw, Bs + q1 * 512);
        {
            float4 a0 = *(const float4*)(xr0 + k0);
            float4 a1 = *(const float4*)(xr0 + k0 + 4);
            *(s16x8*)dst0 = cvt8(a0, a1);
            float4 a2 = *(const float4*)(xr1 + k0);
            float4 a3 = *(const float4*)(xr1 + k0 + 4);
            *(s16x8*)dst1 = cvt8(a2, a3);
        }
        __syncthreads();

        #pragma unroll
        for (int h = 0; h < 2; ++h) {
            const int cb = h * 2 + ksel;
            s16x8 af[2], bf[2];
            #pragma unroll
            for (int i = 0; i < 2; ++i)
                af[i] = *(const s16x8*)&As[rowA[i] * GBK + ((cb ^ swzA[i]) * 8)];
            #pragma unroll
            for (int j = 0; j < 2; ++j)
                bf[j] = *(const s16x8*)&Bs[rowB[j] * GBK + ((cb ^ swzB[j]) * 8)];
            #pragma unroll
            for (int i = 0; i < 2; ++i)
                #pragma unroll
                for (int j = 0; j < 2; ++j)
                    acc[i][j] = __builtin_amdgcn_mfma_f32_32x32x16_bf16(
                        af[i], bf[j], acc[i][j], 0, 0, 0);
        }
        __syncthreads();
    }

    float bi[2];
    #pragma unroll
    for (int j = 0; j < 2; ++j) bi[j] = BiasE[n0 + cw + 32 * j + l32];

    #pragma unroll
    for (int i = 0; i < 2; ++i) {
        #pragma unroll
        for (int reg = 0; reg < 16; ++reg) {
            int rowin = (reg & 3) + 8 * (reg >> 2) + 4 * ksel;
            ushort* crow = Ce + (size_t)(m0 + rw + 32 * i + rowin) * EH1_;
            #pragma unroll
            for (int j = 0; j < 2; ++j) {
                float v = fmaxf(acc[i][j][reg] + bi[j], 0.f);
                crow[n0 + cw + 32 * j + l32] = f2bf(v);
            }
        }
    }
}

#define GYL (E_ + 3)   // 6 l2eo expert slices + 3 gate-table slices

// ---------------------------------------------------------------------------
// Fused expert L2+L3 (verified R8 path) for y<6; gate tiles (dense table,
// fp32-direct A staging) for y>=6.
// ---------------------------------------------------------------------------
__global__ __launch_bounds__(256) void k_l2eog(
        const ushort* __restrict__ h1, const ushort* __restrict__ W2t,
        const float* __restrict__ Eb2, const float* __restrict__ Ew3,
        const float* __restrict__ Eb3, float* __restrict__ eo,
        const float* __restrict__ X, const ushort* __restrict__ Gw1t,
        const float* __restrict__ Gb1, const float* __restrict__ Gw2,
        const float* __restrict__ Gb2, const int* __restrict__ perm,
        const int* __restrict__ histG, const int* __restrict__ gbaseG,
        const int* __restrict__ gtab, const int* __restrict__ ngt,
        float* __restrict__ gate) {
    __shared__ __attribute__((aligned(16))) ushort smem[17408 + 16 * H2P];

    const int t = threadIdx.x;
    const int wave = t >> 6;
    const int lane = t & 63;
    const int quad = lane >> 4;
    const int l16  = lane & 15;
    const int l32  = lane & 31;
    const int ksel = lane >> 5;

    if (blockIdx.y < E_) {
        // ================= L2+L3 branch (verified R8 path) ================
        ushort* As = smem;            // 128*32 elems
        ushort* Bs = smem + 4096;     // 128*32 elems

        const int e = blockIdx.y;
        const ushort* Ae = h1 + (size_t)e * B_ * EH1_;
        const ushort* We = W2t + (size_t)e * EH2_ * EH1_;

        const int m0 = blockIdx.x * 128;

        const int q0 = wave * 2, q1 = q0 + 1;
        const int sr0 = q0 * 16 + (lane >> 2);
        const int sr1 = sr0 + 16;
        const int sw  = ((lane & 3) ^ ((sr0 >> 1) & 3)) * 8;

        const int rw = (wave & 1) * 64;
        const int cw = (wave >> 1) * 64;

        int rowA[2], rowB[2], swzA[2], swzB[2];
        #pragma unroll
        for (int i = 0; i < 2; ++i) {
            rowA[i] = rw + 32 * i + l32;  swzA[i] = (rowA[i] >> 1) & 3;
            rowB[i] = cw + 32 * i + l32;  swzB[i] = (rowB[i] >> 1) & 3;
        }

        f32x16 acc[2][2] = {};

        for (int k0 = 0; k0 < EH1_; k0 += GBK) {
            GLOBAL_LDS16(Ae + (size_t)(m0 + sr0) * EH1_ + k0 + sw, As + q0 * 512);
            GLOBAL_LDS16(Ae + (size_t)(m0 + sr1) * EH1_ + k0 + sw, As + q1 * 512);
            GLOBAL_LDS16(We + (size_t)sr0 * EH1_ + k0 + sw, Bs + q0 * 512);
            GLOBAL_LDS16(We + (size_t)sr1 * EH1_ + k0 + sw, Bs + q1 * 512);
            __syncthreads();

            #pragma unroll
            for (int h = 0; h < 2; ++h) {
                const int cb = h * 2 + ksel;
                s16x8 af[2], bf[2];
                #pragma unroll
                for (int i = 0; i < 2; ++i)
                    af[i] = *(const s16x8*)&As[rowA[i] * GBK + ((cb ^ swzA[i]) * 8)];
                #pragma unroll
                for (int j = 0; j < 2; ++j)
                    bf[j] = *(const s16x8*)&Bs[rowB[j] * GBK + ((cb ^ swzB[j]) * 8)];
                #pragma unroll
                for (int i = 0; i < 2; ++i)
                    #pragma unroll
                    for (int j = 0; j < 2; ++j)
                        acc[i][j] = __builtin_amdgcn_mfma_f32_32x32x16_bf16(
                            af[i], bf[j], acc[i][j], 0, 0, 0);
            }
            __syncthreads();
        }

        // epilogue: h2 tile (bias+relu, bf16) -> LDS, 32x32 C/D scatter
        ushort* h2L = smem;             // [128][H2P]
        ushort* E3t = smem + 128 * H2P; // [16][H2P]

        float bi[2];
        #pragma unroll
        for (int j = 0; j < 2; ++j) bi[j] = Eb2[e * EH2_ + cw + 32 * j + l32];

        #pragma unroll
        for (int i = 0; i < 2; ++i)
            #pragma unroll
            for (int reg = 0; reg < 16; ++reg) {
                int rowin = (reg & 3) + 8 * (reg >> 2) + 4 * ksel;
                int row = rw + 32 * i + rowin;
                #pragma unroll
                for (int j = 0; j < 2; ++j)
                    h2L[row * H2P + cw + 32 * j + l32] =
                        f2bf(fmaxf(acc[i][j][reg] + bi[j], 0.f));
            }

        for (int i = t; i < 16 * 128; i += 256) {
            int col = i >> 7, k = i & 127;
            float v = (col < EO_) ? Ew3[(size_t)e * EH2_ * EO_ + k * EO_ + col] : 0.f;
            E3t[col * H2P + k] = f2bf(v);
        }
        __syncthreads();

        #pragma unroll
        for (int gi = 0; gi < 2; ++gi) {
            int g = wave * 2 + gi;
            f32x4 acc2 = {};
            #pragma unroll
            for (int kc = 0; kc < 4; ++kc) {
                s16x8 a = *(const s16x8*)&h2L[(g * 16 + l16) * H2P + kc * 32 + quad * 8];
                s16x8 b = *(const s16x8*)&E3t[l16 * H2P + kc * 32 + quad * 8];
                acc2 = __builtin_amdgcn_mfma_f32_16x16x32_bf16(a, b, acc2, 0, 0, 0);
            }
            if (l16 < EO_) {
                float b3 = Eb3[e * EO_ + l16];
                #pragma unroll
                for (int r = 0; r < 4; ++r) {
                    int row = m0 + g * 16 + quad * 4 + r;
                    eo[(size_t)row * (E_ * EO_) + e * EO_ + l16] = acc2[r] + b3;
                }
            }
        }
        return;
    }

    // ===================== GATE branch (dense tile table) =================
    {
        const int gidx = (blockIdx.y - E_) * gridDim.x + blockIdx.x;
        if (gidx >= ngt[0]) return;
        const int entry = gtab[gidx];
        const int d     = entry >> 16;
        const int start = (entry & 0xffff) * 64;
        const int base  = gbaseG[d];
        const int cnt   = histG[d];

        // carve gate LDS out of smem (byte offsets; total smem = 39168 B)
        ushort* gAs  = smem;                                   // 4096 B @0
        ushort* gBs  = smem + 2048;                            // 4096 B @4096
        int*    ridx = (int*)(smem + 4096);                    // 256 B  @8192
        float (*gh)[GH_ + 1] = (float(*)[GH_ + 1])(smem + 4224);  // 16640 B @8448
        float*  w2s  = (float*)(smem + 12544);                 // 1536 B @25088
        float*  b2s  = (float*)(smem + 13312);                 // 24 B   @26624
        float (*lg)[E_] = (float(*)[E_])(smem + 13324);        // 1536 B @26648

        const int qsw = (quad ^ ((l16 >> 1) & 3)) * 8;

        if (t < 64) {
            int p = start + t;
            ridx[t] = (p < cnt) ? perm[base + p] : perm[base];  // clamp OOB
        }
        for (int i = t; i < GH_ * E_; i += 256) w2s[i] = Gw2[(size_t)d * GH_ * E_ + i];
        if (t < E_) b2s[t] = Gb2[d * E_ + t];
        __syncthreads();

        const int srow = t >> 2;
        const int sw   = ((t & 3) ^ ((srow >> 1) & 3)) * 8;
        const int myRow = ridx[srow];
        const float*  aRow = X + (size_t)myRow * IN_ + sw;     // fp32 direct
        const ushort* bRow = Gw1t + (size_t)d * GH_ * IN_ + (size_t)srow * IN_ + sw;
        ushort* gdst = gAs + wave * 512 + lane * 8;

        f32x4 acc[4] = {};
        for (int k0 = 0; k0 < IN_; k0 += 32) {
            GLOBAL_LDS16(bRow + k0, gBs + wave * 512);
            {
                float4 a0 = *(const float4*)(aRow + k0);
                float4 a1 = *(const float4*)(aRow + k0 + 4);
                *(s16x8*)gdst = cvt8(a0, a1);
            }
            __syncthreads();

            s16x8 bf = *(const s16x8*)&gBs[(wave * 16 + l16) * 32 + qsw];
            #pragma unroll
            for (int i = 0; i < 4; ++i) {
                s16x8 af = *(const s16x8*)&gAs[(16 * i + l16) * 32 + qsw];
                acc[i] = __builtin_amdgcn_mfma_f32_16x16x32_bf16(af, bf, acc[i], 0, 0, 0);
            }
            __syncthreads();
        }

        const int hcol = wave * 16 + l16;
        float hb = Gb1[d * GH_ + hcol];
        #pragma unroll
        for (int i = 0; i < 4; ++i)
            #pragma unroll
            for (int r = 0; r < 4; ++r)
                gh[16 * i + quad * 4 + r][hcol] = fmaxf(acc[i][r] + hb, 0.f);
        __syncthreads();

        for (int p = t; p < 64 * E_; p += 256) {
            int row = p / E_, e = p - row * E_;
            float s = b2s[e];
            #pragma unroll 8
            for (int h = 0; h < GH_; ++h) s += gh[row][h] * w2s[h * E_ + e];
            lg[row][e] = s;
        }
        __syncthreads();

        if (t < 64 && start + t < cnt) {
            int b = ridx[t];
            float mx = lg[t][0];
            #pragma unroll
            for (int e = 1; e < E_; ++e) mx = fmaxf(mx, lg[t][e]);
            float ex[E_], sum = 0.f;
            #pragma unroll
            for (int e = 0; e < E_; ++e) { ex[e] = expf(lg[t][e] - mx); sum += ex[e]; }
            float inv = 1.f / sum;
            #pragma unroll
            for (int e = 0; e < E_; ++e) gate[(size_t)b * E_ + e] = ex[e] * inv;
        }
    }
}

// ---------------------------------------------------------------------------
// Final: MMoE combine + avg + tower, one wave per sample
// ---------------------------------------------------------------------------
__global__ __launch_bounds__(256) void k_final(
        const float* __restrict__ eo, const float* __restrict__ gate,
        const int* __restrict__ dom,
        const float* __restrict__ Tw1, const float* __restrict__ Tb1,
        const float* __restrict__ Tw2, const float* __restrict__ Tb2,
        float* __restrict__ out) {
    const int wave = threadIdx.x >> 6;
    const int lane = threadIdx.x & 63;
    const int b = blockIdx.x * 4 + wave;
    const int d = dom[b];

    const float* eob = eo + (size_t)b * (E_ * EO_);
    float g[E_];
    #pragma unroll
    for (int e = 0; e < E_; ++e) g[e] = gate[(size_t)b * E_ + e];

    float mmoe[EO_], avg[EO_];
    #pragma unroll
    for (int o = 0; o < EO_; ++o) {
        float m = 0.f, a = 0.f;
        #pragma unroll
        for (int e = 0; e < E_; ++e) {
            float v = eob[e * EO_ + o];
            m += g[e] * v;
            a += v;
        }
        mmoe[o] = m;
        avg[o] = a * (1.0f / E_);
    }

    float acc = Tb1[d * TH_ + lane];
    #pragma unroll
    for (int o = 0; o < EO_; ++o)
        acc += mmoe[o] * Tw1[(size_t)d * EO_ * TH_ + o * TH_ + lane];
    acc = fmaxf(acc, 0.f);

    float s = acc * Tw2[d * TH_ + lane];
    #pragma unroll
    for (int off = 32; off >= 1; off >>= 1) s += __shfl_xor(s, off, 64);

    if (lane == 0)
        out[b] = 1.f / (1.f + expf(-(s + Tb2[d])));
    if (lane < EO_) {
        out[B_ + (size_t)b * EO_ + lane] = avg[lane];
        out[B_ + (size_t)B_ * EO_ + (size_t)b * EO_ + lane] = mmoe[lane];
    }
}

// ---------------------------------------------------------------------------
extern "C" void kernel_launch(void* const* d_in, const int* in_sizes, int n_in,
                              void* d_out, int out_size, void* d_ws, size_t ws_size,
                              hipStream_t stream) {
    const float* x   = (const float*)d_in[0];
    const int*   dom = (const int*)d_in[1];
    const float* Ew1 = (const float*)d_in[2];
    const float* Eb1 = (const float*)d_in[3];
    const float* Ew2 = (const float*)d_in[4];
    const float* Eb2 = (const float*)d_in[5];
    const float* Ew3 = (const float*)d_in[6];
    const float* Eb3 = (const float*)d_in[7];
    const float* Gw1 = (const float*)d_in[8];
    const float* Gb1 = (const float*)d_in[9];
    const float* Gw2 = (const float*)d_in[10];
    const float* Gb2 = (const float*)d_in[11];
    const float* Tw1 = (const float*)d_in[12];
    const float* Tb1 = (const float*)d_in[13];
    const float* Tw2 = (const float*)d_in[14];
    const float* Tb2 = (const float*)d_in[15];
    float* out = (float*)d_out;

    char* ws = (char*)d_ws;
    size_t off = 0;
    auto take = [&](size_t bytes) -> char* {
        char* p = ws + off;
        off = (off + bytes + 255) & ~(size_t)255;
        return p;
    };
    int*    cnts    = (int*)take((size_t)NCHUNK * D_ * 4);
    int*    histG   = (int*)take(D_ * 4);
    int*    gbaseG  = (int*)take(D_ * 4);
    int*    gtab    = (int*)take(512 * 4);
    int*    ngt     = (int*)take(4);
    int*    perm    = (int*)take(B_ * 4);
    float*  gateBuf = (float*)take((size_t)B_ * E_ * 4);
    float*  eoBuf   = (float*)take((size_t)B_ * E_ * EO_ * 4);
    ushort* W1t     = (ushort*)take((size_t)E_ * IN_ * EH1_ * 2);
    ushort* W2t     = (ushort*)take((size_t)E_ * EH1_ * EH2_ * 2);
    ushort* G1t     = (ushort*)take((size_t)D_ * IN_ * GH_ * 2);
    ushort* h1      = (ushort*)take((size_t)E_ * B_ * EH1_ * 2);

    // 1) weight transposes + per-chunk counts (x conversion eliminated)
    k_prep<<<dim3(PREP_BLKS), dim3(256), 0, stream>>>(
        Ew1, W1t, Ew2, W2t, Gw1, G1t, dom, cnts);

    // 2) L1 GEMM (fp32-direct A, all experts); scatter prologue on 64 blocks
    k_gemm<<<dim3(EH1_ / 128, B_ / 128, E_), dim3(256), 0, stream>>>(
        x, W1t, Eb1, h1, dom, cnts, perm, gbaseG, histG, gtab, ngt);

    // 3) fused L2+L3 (y<6) + gates (y>=6, dense table, fp32-direct A)
    k_l2eog<<<dim3(B_ / 128, GYL), dim3(256), 0, stream>>>(
        h1, W2t, Eb2, Ew3, Eb3, eoBuf,
        x, G1t, Gb1, Gw2, Gb2, perm, histG, gbaseG, gtab, ngt, gateBuf);

    // 4) combine + towers + outputs
    k_final<<<dim3(B_ / 4), dim3(256), 0, stream>>>(
        eoBuf, gateBuf, dom, Tw1, Tb1, Tw2, Tb2, out);
}

// Round 10
// 245.283 us; speedup vs baseline: 1.1110x; 1.1110x over previous
//
#include <hip/hip_runtime.h>
#include <hip/hip_bf16.h>
#include <math.h>

// Problem constants (HC2MMoE)
#define B_    16384
#define IN_   1024
#define E_    6
#define D_    20
#define EH1_  256
#define EH2_  128
#define EO_   10
#define GH_   64
#define TH_   64

typedef short  s16x8  __attribute__((ext_vector_type(8)));   // 8 bf16 = 4 VGPRs
typedef float  f32x4  __attribute__((ext_vector_type(4)));
typedef float  f32x16 __attribute__((ext_vector_type(16)));

__device__ inline ushort f2bf(float f) {   // RNE fp32 -> bf16 bits
    union { float f; uint32_t u; } v; v.f = f;
    return (ushort)((v.u + 0x7fffu + ((v.u >> 16) & 1u)) >> 16);
}

#define GLOBAL_LDS16(g, l)                                                     \
    __builtin_amdgcn_global_load_lds(                                          \
        (const __attribute__((address_space(1))) void*)(g),                    \
        (__attribute__((address_space(3))) void*)(l), 16, 0, 0)

#define NCHUNK (B_ / 256)   // 64

// ---------------------------------------------------------------------------
// Prep (R6-verified): x-convert (grid-strided; cvt measured ~8us via R9
// subtraction — keep it, bf16 xb halves GEMM A-traffic) + 3 weight
// transposes + per-chunk domain counts.
// ---------------------------------------------------------------------------
#define CVT_BLKS  2048
#define CVT_ITERS (B_ * IN_ / 4 / 256 / CVT_BLKS)            // 8
#define WT1_TILES ((EH1_ / 32) * (IN_ / 32) * E_)            // 1536
#define WT2_TILES ((EH2_ / 32) * (EH1_ / 32) * E_)           // 192
#define WTG_TILES ((GH_ / 32) * (IN_ / 32) * D_)             // 1280
#define PREP_BLKS (CVT_BLKS + WT1_TILES + WT2_TILES + WTG_TILES + NCHUNK)

__global__ __launch_bounds__(256) void k_prep(
        const float* __restrict__ x, ushort* __restrict__ xb,
        const float* __restrict__ Ew1, ushort* __restrict__ W1t,
        const float* __restrict__ Ew2, ushort* __restrict__ W2t,
        const float* __restrict__ Gw1, ushort* __restrict__ G1t,
        const int* __restrict__ dom, int* __restrict__ cnts) {
    __shared__ float tile[32][33];
    __shared__ int hcnt[D_];
    int bid = blockIdx.x;
    const int t = threadIdx.x;

    if (bid < CVT_BLKS) {
        int i = bid * 256 + t;
        #pragma unroll
        for (int it = 0; it < CVT_ITERS; ++it, i += CVT_BLKS * 256) {
            float4 v = ((const float4*)x)[i];
            ushort4 o;
            o.x = f2bf(v.x); o.y = f2bf(v.y); o.z = f2bf(v.z); o.w = f2bf(v.w);
            ((ushort4*)xb)[i] = o;
        }
        return;
    }
    bid -= CVT_BLKS;

    const float* W; ushort* Wt; int K, N, z, ky, nx;
    if (bid < WT1_TILES) {
        W = Ew1; Wt = W1t; K = IN_; N = EH1_;
        z = bid / (8 * 32); int r = bid % (8 * 32); ky = r / 8; nx = r % 8;
    } else if (bid < WT1_TILES + WT2_TILES) {
        bid -= WT1_TILES;
        W = Ew2; Wt = W2t; K = EH1_; N = EH2_;
        z = bid / (4 * 8); int r = bid % (4 * 8); ky = r / 4; nx = r % 4;
    } else if (bid < WT1_TILES + WT2_TILES + WTG_TILES) {
        bid -= WT1_TILES + WT2_TILES;
        W = Gw1; Wt = G1t; K = IN_; N = GH_;
        z = bid / (2 * 32); int r = bid % (2 * 32); ky = r / 2; nx = r % 2;
    } else {
        // per-chunk count blocks: 256 samples each, LDS counts -> direct write
        int c = bid - (WT1_TILES + WT2_TILES + WTG_TILES);
        if (t < D_) hcnt[t] = 0;
        __syncthreads();
        atomicAdd(&hcnt[dom[c * 256 + t]], 1);
        __syncthreads();
        if (t < D_) cnts[c * D_ + t] = hcnt[t];
        return;
    }
    const int n0 = nx * 32, k0 = ky * 32;
    const float* We = W + (size_t)z * K * N;
    ushort* Wte = Wt + (size_t)z * K * N;
    const int lx = t & 31, ly = t >> 5;
    #pragma unroll
    for (int r = 0; r < 4; ++r)
        tile[ly + r * 8][lx] = We[(size_t)(k0 + ly + r * 8) * N + n0 + lx];
    __syncthreads();
    #pragma unroll
    for (int r = 0; r < 4; ++r)
        Wte[(size_t)(n0 + ly + r * 8) * K + k0 + lx] = f2bf(tile[lx][ly + r * 8]);
}

#define GBK 32
#define H2P 136

// ---------------------------------------------------------------------------
// L1 GEMM (R6-verified 128x128/BK=32/256t, 72.6us). Scatter prologue on 64
// resident blocks. Grid (2,128,6)=1536 = residency capacity exactly.
// ---------------------------------------------------------------------------
__global__ __launch_bounds__(256) void k_gemm(
        const ushort* __restrict__ A, const ushort* __restrict__ Wt,
        const float* __restrict__ Bias, ushort* __restrict__ C,
        const int* __restrict__ dom, const int* __restrict__ cnts,
        int* __restrict__ perm, int* __restrict__ gbaseG,
        int* __restrict__ histG, int* __restrict__ gtab,
        int* __restrict__ ngt) {
    __shared__ __attribute__((aligned(16))) ushort As[128 * GBK];
    __shared__ __attribute__((aligned(16))) ushort Bs[128 * GBK];

    const int t = threadIdx.x;

    if (blockIdx.z == 0 && blockIdx.x == 0 && blockIdx.y < NCHUNK) {
        // ---------- scatter prologue (LDS aliases As; done before staging) --
        int* cl    = (int*)As;              // [NCHUNK*D_] = 1280 ints (5120B)
        int* tot   = cl + NCHUNK * D_;      // [D_]
        int* lbase = tot + D_;              // [D_]
        int* lcnt  = lbase + D_;            // [D_]
        const int c = blockIdx.y;

        for (int i = t; i < NCHUNK * D_; i += 256) cl[i] = cnts[i];
        __syncthreads();
        if (t < D_) {
            int before = 0, total = 0;
            #pragma unroll 8
            for (int cc = 0; cc < NCHUNK; ++cc) {
                int v = cl[cc * D_ + t];
                if (cc < c) before += v;
                total += v;
            }
            tot[t] = total; lbase[t] = before; lcnt[t] = 0;
        }
        __syncthreads();
        if (t < D_) {
            int gb = 0;
            #pragma unroll
            for (int d2 = 0; d2 < D_; ++d2) if (d2 < t) gb += tot[d2];
            lbase[t] += gb;
            if (c == 0) { gbaseG[t] = gb; histG[t] = tot[t]; }
        }
        __syncthreads();
        if (c == 0 && t < D_) {
            // parallel gate-table build: thread t owns domain t's entries
            int off = 0, nt = (tot[t] + 63) >> 6;
            #pragma unroll
            for (int d2 = 0; d2 < D_; ++d2)
                if (d2 < t) off += (tot[d2] + 63) >> 6;
            for (int tt = 0; tt < nt; ++tt) gtab[off + tt] = (t << 16) | tt;
            if (t == D_ - 1) ngt[0] = off + nt;
        }
        {
            const int g = c * 256 + t;
            const int d = dom[g];
            int r = atomicAdd(&lcnt[d], 1);     // LDS-only rank within chunk
            perm[lbase[d] + r] = g;
        }
        __syncthreads();   // As safe to reuse for GEMM staging
    }

    // ---------------- expert L1 GEMM (byte-identical to verified R6) ------
    const int e = blockIdx.z;
    const ushort* Ae = A;
    const ushort* We = Wt + (size_t)e * (size_t)EH1_ * IN_;
    const float* BiasE = Bias + (size_t)e * EH1_;
    ushort* Ce = C + (size_t)e * (size_t)B_ * EH1_;

    const int m0 = blockIdx.y * 128;
    const int n0 = blockIdx.x * 128;
    const int wave = t >> 6;
    const int lane = t & 63;

    const int q0 = wave * 2, q1 = q0 + 1;
    const int sr0 = q0 * 16 + (lane >> 2);
    const int sr1 = sr0 + 16;
    const int sw  = ((lane & 3) ^ ((sr0 >> 1) & 3)) * 8;

    const int l32  = lane & 31;
    const int ksel = lane >> 5;
    const int rw = (wave & 1) * 64;
    const int cw = (wave >> 1) * 64;

    int rowA[2], rowB[2], swzA[2], swzB[2];
    #pragma unroll
    for (int i = 0; i < 2; ++i) {
        rowA[i] = rw + 32 * i + l32;  swzA[i] = (rowA[i] >> 1) & 3;
        rowB[i] = cw + 32 * i + l32;  swzB[i] = (rowB[i] >> 1) & 3;
    }

    f32x16 acc[2][2] = {};

    for (int k0 = 0; k0 < IN_; k0 += GBK) {
        GLOBAL_LDS16(Ae + (size_t)(m0 + sr0) * IN_ + k0 + sw, As + q0 * 512);
        GLOBAL_LDS16(Ae + (size_t)(m0 + sr1) * IN_ + k0 + sw, As + q1 * 512);
        GLOBAL_LDS16(We + (size_t)(n0 + sr0) * IN_ + k0 + sw, Bs + q0 * 512);
        GLOBAL_LDS16(We + (size_t)(n0 + sr1) * IN_ + k0 + sw, Bs + q1 * 512);
        __syncthreads();

        #pragma unroll
        for (int h = 0; h < 2; ++h) {
            const int cb = h * 2 + ksel;
            s16x8 af[2], bf[2];
            #pragma unroll
            for (int i = 0; i < 2; ++i)
                af[i] = *(const s16x8*)&As[rowA[i] * GBK + ((cb ^ swzA[i]) * 8)];
            #pragma unroll
            for (int j = 0; j < 2; ++j)
                bf[j] = *(const s16x8*)&Bs[rowB[j] * GBK + ((cb ^ swzB[j]) * 8)];
            #pragma unroll
            for (int i = 0; i < 2; ++i)
                #pragma unroll
                for (int j = 0; j < 2; ++j)
                    acc[i][j] = __builtin_amdgcn_mfma_f32_32x32x16_bf16(
                        af[i], bf[j], acc[i][j], 0, 0, 0);
        }
        __syncthreads();
    }

    float bi[2];
    #pragma unroll
    for (int j = 0; j < 2; ++j) bi[j] = BiasE[n0 + cw + 32 * j + l32];

    #pragma unroll
    for (int i = 0; i < 2; ++i) {
        #pragma unroll
        for (int reg = 0; reg < 16; ++reg) {
            int rowin = (reg & 3) + 8 * (reg >> 2) + 4 * ksel;
            ushort* crow = Ce + (size_t)(m0 + rw + 32 * i + rowin) * EH1_;
            #pragma unroll
            for (int j = 0; j < 2; ++j) {
                float v = fmaxf(acc[i][j][reg] + bi[j], 0.f);
                crow[n0 + cw + 32 * j + l32] = f2bf(v);
            }
        }
    }
}

// ---------------------------------------------------------------------------
// Gate (standalone, R10): dense tile table, grid 512x1 (~276 active), 28KB
// LDS -> 5/CU -> single generation. Split from l2eog because the merged
// 1152-block grid at 39KB LDS exceeded the 1024-block residency capacity
// (2 dispatch generations, R5-lesson tail).
// ---------------------------------------------------------------------------
__global__ __launch_bounds__(256) void k_gate(
        const ushort* __restrict__ xb, const ushort* __restrict__ Gw1t,
        const float* __restrict__ Gb1, const float* __restrict__ Gw2,
        const float* __restrict__ Gb2, const int* __restrict__ perm,
        const int* __restrict__ histG, const int* __restrict__ gbaseG,
        const int* __restrict__ gtab, const int* __restrict__ ngt,
        float* __restrict__ gate) {
    __shared__ __attribute__((aligned(16))) ushort gAs[64 * 32];
    __shared__ __attribute__((aligned(16))) ushort gBs[64 * 32];
    __shared__ int    ridx[64];
    __shared__ float  gh[64][GH_ + 1];
    __shared__ float  w2s[GH_ * E_];
    __shared__ float  b2s[E_];
    __shared__ float  lg[64][E_];

    const int gidx = blockIdx.x;
    if (gidx >= ngt[0]) return;
    const int entry = gtab[gidx];
    const int d     = entry >> 16;
    const int start = (entry & 0xffff) * 64;
    const int base  = gbaseG[d];
    const int cnt   = histG[d];

    const int t = threadIdx.x;
    const int wave = t >> 6;
    const int lane = t & 63;
    const int quad = lane >> 4;
    const int l16  = lane & 15;
    const int qsw  = (quad ^ ((l16 >> 1) & 3)) * 8;

    if (t < 64) {
        int p = start + t;
        ridx[t] = (p < cnt) ? perm[base + p] : perm[base];  // clamp OOB
    }
    for (int i = t; i < GH_ * E_; i += 256) w2s[i] = Gw2[(size_t)d * GH_ * E_ + i];
    if (t < E_) b2s[t] = Gb2[d * E_ + t];
    __syncthreads();

    const int srow = t >> 2;
    const int sw   = ((t & 3) ^ ((srow >> 1) & 3)) * 8;
    const int myRow = ridx[srow];
    const ushort* aRow = xb + (size_t)myRow * IN_ + sw;
    const ushort* bRow = Gw1t + (size_t)d * GH_ * IN_ + (size_t)srow * IN_ + sw;

    f32x4 acc[4] = {};
    for (int k0 = 0; k0 < IN_; k0 += 32) {
        GLOBAL_LDS16(aRow + k0, gAs + wave * 512);
        GLOBAL_LDS16(bRow + k0, gBs + wave * 512);
        __syncthreads();

        s16x8 bf = *(const s16x8*)&gBs[(wave * 16 + l16) * 32 + qsw];
        #pragma unroll
        for (int i = 0; i < 4; ++i) {
            s16x8 af = *(const s16x8*)&gAs[(16 * i + l16) * 32 + qsw];
            acc[i] = __builtin_amdgcn_mfma_f32_16x16x32_bf16(af, bf, acc[i], 0, 0, 0);
        }
        __syncthreads();
    }

    const int hcol = wave * 16 + l16;
    float hb = Gb1[d * GH_ + hcol];
    #pragma unroll
    for (int i = 0; i < 4; ++i)
        #pragma unroll
        for (int r = 0; r < 4; ++r)
            gh[16 * i + quad * 4 + r][hcol] = fmaxf(acc[i][r] + hb, 0.f);
    __syncthreads();

    for (int p = t; p < 64 * E_; p += 256) {
        int row = p / E_, e = p - row * E_;
        float s = b2s[e];
        #pragma unroll 8
        for (int h = 0; h < GH_; ++h) s += gh[row][h] * w2s[h * E_ + e];
        lg[row][e] = s;
    }
    __syncthreads();

    if (t < 64 && start + t < cnt) {
        int b = ridx[t];
        float mx = lg[t][0];
        #pragma unroll
        for (int e = 1; e < E_; ++e) mx = fmaxf(mx, lg[t][e]);
        float ex[E_], sum = 0.f;
        #pragma unroll
        for (int e = 0; e < E_; ++e) { ex[e] = expf(lg[t][e] - mx); sum += ex[e]; }
        float inv = 1.f / sum;
        #pragma unroll
        for (int e = 0; e < E_; ++e) gate[(size_t)b * E_ + e] = ex[e] * inv;
    }
}

// ---------------------------------------------------------------------------
// Fused expert L2+L3 (verified path), grid (128,6) = 768 blocks at 39KB LDS
// -> 4/CU -> 1024 capacity -> SINGLE dispatch generation.
// ---------------------------------------------------------------------------
__global__ __launch_bounds__(256) void k_l2eo(
        const ushort* __restrict__ h1, const ushort* __restrict__ W2t,
        const float* __restrict__ Eb2, const float* __restrict__ Ew3,
        const float* __restrict__ Eb3, float* __restrict__ eo) {
    __shared__ __attribute__((aligned(16))) ushort smem[17408 + 16 * H2P];

    const int t = threadIdx.x;
    const int wave = t >> 6;
    const int lane = t & 63;
    const int quad = lane >> 4;
    const int l16  = lane & 15;
    const int l32  = lane & 31;
    const int ksel = lane >> 5;

    ushort* As = smem;            // 128*32 elems
    ushort* Bs = smem + 4096;     // 128*32 elems

    const int e = blockIdx.y;
    const ushort* Ae = h1 + (size_t)e * B_ * EH1_;
    const ushort* We = W2t + (size_t)e * EH2_ * EH1_;

    const int m0 = blockIdx.x * 128;

    const int q0 = wave * 2, q1 = q0 + 1;
    const int sr0 = q0 * 16 + (lane >> 2);
    const int sr1 = sr0 + 16;
    const int sw  = ((lane & 3) ^ ((sr0 >> 1) & 3)) * 8;

    const int rw = (wave & 1) * 64;
    const int cw = (wave >> 1) * 64;

    int rowA[2], rowB[2], swzA[2], swzB[2];
    #pragma unroll
    for (int i = 0; i < 2; ++i) {
        rowA[i] = rw + 32 * i + l32;  swzA[i] = (rowA[i] >> 1) & 3;
        rowB[i] = cw + 32 * i + l32;  swzB[i] = (rowB[i] >> 1) & 3;
    }

    f32x16 acc[2][2] = {};

    for (int k0 = 0; k0 < EH1_; k0 += GBK) {
        GLOBAL_LDS16(Ae + (size_t)(m0 + sr0) * EH1_ + k0 + sw, As + q0 * 512);
        GLOBAL_LDS16(Ae + (size_t)(m0 + sr1) * EH1_ + k0 + sw, As + q1 * 512);
        GLOBAL_LDS16(We + (size_t)sr0 * EH1_ + k0 + sw, Bs + q0 * 512);
        GLOBAL_LDS16(We + (size_t)sr1 * EH1_ + k0 + sw, Bs + q1 * 512);
        __syncthreads();

        #pragma unroll
        for (int h = 0; h < 2; ++h) {
            const int cb = h * 2 + ksel;
            s16x8 af[2], bf[2];
            #pragma unroll
            for (int i = 0; i < 2; ++i)
                af[i] = *(const s16x8*)&As[rowA[i] * GBK + ((cb ^ swzA[i]) * 8)];
            #pragma unroll
            for (int j = 0; j < 2; ++j)
                bf[j] = *(const s16x8*)&Bs[rowB[j] * GBK + ((cb ^ swzB[j]) * 8)];
            #pragma unroll
            for (int i = 0; i < 2; ++i)
                #pragma unroll
                for (int j = 0; j < 2; ++j)
                    acc[i][j] = __builtin_amdgcn_mfma_f32_32x32x16_bf16(
                        af[i], bf[j], acc[i][j], 0, 0, 0);
        }
        __syncthreads();
    }

    // epilogue: h2 tile (bias+relu, bf16) -> LDS, 32x32 C/D scatter
    ushort* h2L = smem;             // [128][H2P]
    ushort* E3t = smem + 128 * H2P; // [16][H2P]

    float bi[2];
    #pragma unroll
    for (int j = 0; j < 2; ++j) bi[j] = Eb2[e * EH2_ + cw + 32 * j + l32];

    #pragma unroll
    for (int i = 0; i < 2; ++i)
        #pragma unroll
        for (int reg = 0; reg < 16; ++reg) {
            int rowin = (reg & 3) + 8 * (reg >> 2) + 4 * ksel;
            int row = rw + 32 * i + rowin;
            #pragma unroll
            for (int j = 0; j < 2; ++j)
                h2L[row * H2P + cw + 32 * j + l32] =
                    f2bf(fmaxf(acc[i][j][reg] + bi[j], 0.f));
        }

    for (int i = t; i < 16 * 128; i += 256) {
        int col = i >> 7, k = i & 127;
        float v = (col < EO_) ? Ew3[(size_t)e * EH2_ * EO_ + k * EO_ + col] : 0.f;
        E3t[col * H2P + k] = f2bf(v);
    }
    __syncthreads();

    #pragma unroll
    for (int gi = 0; gi < 2; ++gi) {
        int g = wave * 2 + gi;
        f32x4 acc2 = {};
        #pragma unroll
        for (int kc = 0; kc < 4; ++kc) {
            s16x8 a = *(const s16x8*)&h2L[(g * 16 + l16) * H2P + kc * 32 + quad * 8];
            s16x8 b = *(const s16x8*)&E3t[l16 * H2P + kc * 32 + quad * 8];
            acc2 = __builtin_amdgcn_mfma_f32_16x16x32_bf16(a, b, acc2, 0, 0, 0);
        }
        if (l16 < EO_) {
            float b3 = Eb3[e * EO_ + l16];
            #pragma unroll
            for (int r = 0; r < 4; ++r) {
                int row = m0 + g * 16 + quad * 4 + r;
                eo[(size_t)row * (E_ * EO_) + e * EO_ + l16] = acc2[r] + b3;
            }
        }
    }
}

// ---------------------------------------------------------------------------
// Final: MMoE combine + avg + tower, one wave per sample
// ---------------------------------------------------------------------------
__global__ __launch_bounds__(256) void k_final(
        const float* __restrict__ eo, const float* __restrict__ gate,
        const int* __restrict__ dom,
        const float* __restrict__ Tw1, const float* __restrict__ Tb1,
        const float* __restrict__ Tw2, const float* __restrict__ Tb2,
        float* __restrict__ out) {
    const int wave = threadIdx.x >> 6;
    const int lane = threadIdx.x & 63;
    const int b = blockIdx.x * 4 + wave;
    const int d = dom[b];

    const float* eob = eo + (size_t)b * (E_ * EO_);
    float g[E_];
    #pragma unroll
    for (int e = 0; e < E_; ++e) g[e] = gate[(size_t)b * E_ + e];

    float mmoe[EO_], avg[EO_];
    #pragma unroll
    for (int o = 0; o < EO_; ++o) {
        float m = 0.f, a = 0.f;
        #pragma unroll
        for (int e = 0; e < E_; ++e) {
            float v = eob[e * EO_ + o];
            m += g[e] * v;
            a += v;
        }
        mmoe[o] = m;
        avg[o] = a * (1.0f / E_);
    }

    float acc = Tb1[d * TH_ + lane];
    #pragma unroll
    for (int o = 0; o < EO_; ++o)
        acc += mmoe[o] * Tw1[(size_t)d * EO_ * TH_ + o * TH_ + lane];
    acc = fmaxf(acc, 0.f);

    float s = acc * Tw2[d * TH_ + lane];
    #pragma unroll
    for (int off = 32; off >= 1; off >>= 1) s += __shfl_xor(s, off, 64);

    if (lane == 0)
        out[b] = 1.f / (1.f + expf(-(s + Tb2[d])));
    if (lane < EO_) {
        out[B_ + (size_t)b * EO_ + lane] = avg[lane];
        out[B_ + (size_t)B_ * EO_ + (size_t)b * EO_ + lane] = mmoe[lane];
    }
}

// ---------------------------------------------------------------------------
extern "C" void kernel_launch(void* const* d_in, const int* in_sizes, int n_in,
                              void* d_out, int out_size, void* d_ws, size_t ws_size,
                              hipStream_t stream) {
    const float* x   = (const float*)d_in[0];
    const int*   dom = (const int*)d_in[1];
    const float* Ew1 = (const float*)d_in[2];
    const float* Eb1 = (const float*)d_in[3];
    const float* Ew2 = (const float*)d_in[4];
    const float* Eb2 = (const float*)d_in[5];
    const float* Ew3 = (const float*)d_in[6];
    const float* Eb3 = (const float*)d_in[7];
    const float* Gw1 = (const float*)d_in[8];
    const float* Gb1 = (const float*)d_in[9];
    const float* Gw2 = (const float*)d_in[10];
    const float* Gb2 = (const float*)d_in[11];
    const float* Tw1 = (const float*)d_in[12];
    const float* Tb1 = (const float*)d_in[13];
    const float* Tw2 = (const float*)d_in[14];
    const float* Tb2 = (const float*)d_in[15];
    float* out = (float*)d_out;

    char* ws = (char*)d_ws;
    size_t off = 0;
    auto take = [&](size_t bytes) -> char* {
        char* p = ws + off;
        off = (off + bytes + 255) & ~(size_t)255;
        return p;
    };
    int*    cnts    = (int*)take((size_t)NCHUNK * D_ * 4);
    int*    histG   = (int*)take(D_ * 4);
    int*    gbaseG  = (int*)take(D_ * 4);
    int*    gtab    = (int*)take(512 * 4);
    int*    ngt     = (int*)take(4);
    int*    perm    = (int*)take(B_ * 4);
    float*  gateBuf = (float*)take((size_t)B_ * E_ * 4);
    float*  eoBuf   = (float*)take((size_t)B_ * E_ * EO_ * 4);
    ushort* xb      = (ushort*)take((size_t)B_ * IN_ * 2);
    ushort* W1t     = (ushort*)take((size_t)E_ * IN_ * EH1_ * 2);
    ushort* W2t     = (ushort*)take((size_t)E_ * EH1_ * EH2_ * 2);
    ushort* G1t     = (ushort*)take((size_t)D_ * IN_ * GH_ * 2);
    ushort* h1      = (ushort*)take((size_t)E_ * B_ * EH1_ * 2);

    // 1) conversions + transposes + per-chunk counts (R6-verified)
    k_prep<<<dim3(PREP_BLKS), dim3(256), 0, stream>>>(
        x, xb, Ew1, W1t, Ew2, W2t, Gw1, G1t, dom, cnts);

    // 2) L1 GEMM (all experts); scatter prologue on 64 resident blocks
    k_gemm<<<dim3(EH1_ / 128, B_ / 128, E_), dim3(256), 0, stream>>>(
        xb, W1t, Eb1, h1, dom, cnts, perm, gbaseG, histG, gtab, ngt);

    // 3) gate (dense table, single generation)
    k_gate<<<dim3(512), dim3(256), 0, stream>>>(
        xb, G1t, Gb1, Gw2, Gb2, perm, histG, gbaseG, gtab, ngt, gateBuf);

    // 4) fused L2+L3 (768 blocks <= 1024 capacity -> single generation)
    k_l2eo<<<dim3(B_ / 128, E_), dim3(256), 0, stream>>>(
        h1, W2t, Eb2, Ew3, Eb3, eoBuf);

    // 5) combine + towers + outputs
    k_final<<<dim3(B_ / 4), dim3(256), 0, stream>>>(
        eoBuf, gateBuf, dom, Tw1, Tb1, Tw2, Tb2, out);
}

// Round 11
// 240.342 us; speedup vs baseline: 1.1338x; 1.0206x over previous
//
#include <hip/hip_runtime.h>
#include <hip/hip_bf16.h>
#include <math.h>

// Problem constants (HC2MMoE)
#define B_    16384
#define IN_   1024
#define E_    6
#define D_    20
#define EH1_  256
#define EH2_  128
#define EO_   10
#define GH_   64
#define TH_   64

typedef short  s16x8  __attribute__((ext_vector_type(8)));   // 8 bf16 = 4 VGPRs
typedef float  f32x4  __attribute__((ext_vector_type(4)));
typedef float  f32x16 __attribute__((ext_vector_type(16)));

__device__ inline ushort f2bf(float f) {   // RNE fp32 -> bf16 bits
    union { float f; uint32_t u; } v; v.f = f;
    return (ushort)((v.u + 0x7fffu + ((v.u >> 16) & 1u)) >> 16);
}

#define GLOBAL_LDS16(g, l)                                                     \
    __builtin_amdgcn_global_load_lds(                                          \
        (const __attribute__((address_space(1))) void*)(g),                    \
        (__attribute__((address_space(3))) void*)(l), 16, 0, 0)

#define NCHUNK (B_ / 256)   // 64

// ---------------------------------------------------------------------------
// Prep (R11): x-convert (grid-strided, R6-verified) + 3 weight transposes in
// 64x64 tiles (4x fewer blocks than 32x32; writes 128B/wave-group, reads
// 256B; [64][65] pad -> max 2-way bank alias = free) + per-chunk counts.
// ---------------------------------------------------------------------------
#define CVT_BLKS  2048
#define CVT_ITERS (B_ * IN_ / 4 / 256 / CVT_BLKS)            // 8
#define WT1_T64 (E_ * (EH1_ / 64) * (IN_ / 64))              // 384
#define WT2_T64 (E_ * (EH2_ / 64) * (EH1_ / 64))             // 48
#define WTG_T64 (D_ * (GH_ / 64) * (IN_ / 64))               // 320
#define PREP_BLKS (CVT_BLKS + WT1_T64 + WT2_T64 + WTG_T64 + NCHUNK)

__global__ __launch_bounds__(256) void k_prep(
        const float* __restrict__ x, ushort* __restrict__ xb,
        const float* __restrict__ Ew1, ushort* __restrict__ W1t,
        const float* __restrict__ Ew2, ushort* __restrict__ W2t,
        const float* __restrict__ Gw1, ushort* __restrict__ G1t,
        const int* __restrict__ dom, int* __restrict__ cnts) {
    __shared__ float tile[64][65];
    __shared__ int hcnt[D_];
    int bid = blockIdx.x;
    const int t = threadIdx.x;

    if (bid < CVT_BLKS) {
        int i = bid * 256 + t;
        #pragma unroll
        for (int it = 0; it < CVT_ITERS; ++it, i += CVT_BLKS * 256) {
            float4 v = ((const float4*)x)[i];
            ushort4 o;
            o.x = f2bf(v.x); o.y = f2bf(v.y); o.z = f2bf(v.z); o.w = f2bf(v.w);
            ((ushort4*)xb)[i] = o;
        }
        return;
    }
    bid -= CVT_BLKS;

    const float* W; ushort* Wt; int K, N, z, ky, nx;
    if (bid < WT1_T64) {
        W = Ew1; Wt = W1t; K = IN_; N = EH1_;
        z = bid / (4 * 16); int r = bid % (4 * 16); ky = r / 4; nx = r % 4;
    } else if (bid < WT1_T64 + WT2_T64) {
        bid -= WT1_T64;
        W = Ew2; Wt = W2t; K = EH1_; N = EH2_;
        z = bid / (2 * 4); int r = bid % (2 * 4); ky = r / 2; nx = r % 2;
    } else if (bid < WT1_T64 + WT2_T64 + WTG_T64) {
        bid -= WT1_T64 + WT2_T64;
        W = Gw1; Wt = G1t; K = IN_; N = GH_;
        z = bid / 16; ky = bid % 16; nx = 0;
    } else {
        // per-chunk count blocks: 256 samples each, LDS counts -> direct write
        int c = bid - (WT1_T64 + WT2_T64 + WTG_T64);
        if (t < D_) hcnt[t] = 0;
        __syncthreads();
        atomicAdd(&hcnt[dom[c * 256 + t]], 1);
        __syncthreads();
        if (t < D_) cnts[c * D_ + t] = hcnt[t];
        return;
    }
    const int n0 = nx * 64, k0 = ky * 64;
    const float* We = W + (size_t)z * K * N;
    ushort* Wte = Wt + (size_t)z * K * N;
    const int lx = t & 63, ly = t >> 6;          // ly: 0..3, 16 rows each
    #pragma unroll
    for (int r = 0; r < 16; ++r)
        tile[ly * 16 + r][lx] = We[(size_t)(k0 + ly * 16 + r) * N + n0 + lx];
    __syncthreads();
    #pragma unroll
    for (int r = 0; r < 16; ++r)
        Wte[(size_t)(n0 + ly * 16 + r) * K + k0 + lx] =
            f2bf(tile[lx][ly * 16 + r]);
}

#define GBK 32
#define H2P 136

// ---------------------------------------------------------------------------
// L1 GEMM (R6-verified 128x128/BK=32/256t body) + XCD-aware block remap:
// linear id l -> q=l%8 (XCD under round-robin), rank r=l/8;
// by = q*16 + (r&15), bx = (r>>4)&1, bz = r>>5.  All 12 blocks sharing an
// A-panel (2 n-tiles x 6 experts) land on one XCD; per-XCD A working set
// 33MB -> 4MB (~L2 size). Bijective: 8*16*2*6 = 1536 = grid exactly.
// Scatter prologue on the 64 remapped (bz==0,bx==0,by<64) blocks.
// ---------------------------------------------------------------------------
__global__ __launch_bounds__(256) void k_gemm(
        const ushort* __restrict__ A, const ushort* __restrict__ Wt,
        const float* __restrict__ Bias, ushort* __restrict__ C,
        const int* __restrict__ dom, const int* __restrict__ cnts,
        int* __restrict__ perm, int* __restrict__ gbaseG,
        int* __restrict__ histG, int* __restrict__ gtab,
        int* __restrict__ ngt) {
    __shared__ __attribute__((aligned(16))) ushort As[128 * GBK];
    __shared__ __attribute__((aligned(16))) ushort Bs[128 * GBK];

    const int t = threadIdx.x;

    // XCD remap (grid is (2,128,6); HW dispatch order: x fastest)
    const int lin = blockIdx.x + 2 * blockIdx.y + 256 * blockIdx.z;
    const int q  = lin & 7;
    const int rr = lin >> 3;                 // 0..191
    const int by = q * 16 + (rr & 15);
    const int bx = (rr >> 4) & 1;
    const int bz = rr >> 5;                  // 0..5

    if (bz == 0 && bx == 0 && by < NCHUNK) {
        // ---------- scatter prologue (LDS aliases As; done before staging) --
        int* cl    = (int*)As;              // [NCHUNK*D_] = 1280 ints (5120B)
        int* tot   = cl + NCHUNK * D_;      // [D_]
        int* lbase = tot + D_;              // [D_]
        int* lcnt  = lbase + D_;            // [D_]
        const int c = by;

        for (int i = t; i < NCHUNK * D_; i += 256) cl[i] = cnts[i];
        __syncthreads();
        if (t < D_) {
            int before = 0, total = 0;
            #pragma unroll 8
            for (int cc = 0; cc < NCHUNK; ++cc) {
                int v = cl[cc * D_ + t];
                if (cc < c) before += v;
                total += v;
            }
            tot[t] = total; lbase[t] = before; lcnt[t] = 0;
        }
        __syncthreads();
        if (t < D_) {
            int gb = 0;
            #pragma unroll
            for (int d2 = 0; d2 < D_; ++d2) if (d2 < t) gb += tot[d2];
            lbase[t] += gb;
            if (c == 0) { gbaseG[t] = gb; histG[t] = tot[t]; }
        }
        __syncthreads();
        if (c == 0 && t < D_) {
            // parallel gate-table build: thread t owns domain t's entries
            int off = 0, nt = (tot[t] + 63) >> 6;
            #pragma unroll
            for (int d2 = 0; d2 < D_; ++d2)
                if (d2 < t) off += (tot[d2] + 63) >> 6;
            for (int tt = 0; tt < nt; ++tt) gtab[off + tt] = (t << 16) | tt;
            if (t == D_ - 1) ngt[0] = off + nt;
        }
        {
            const int g = c * 256 + t;
            const int d = dom[g];
            int r = atomicAdd(&lcnt[d], 1);     // LDS-only rank within chunk
            perm[lbase[d] + r] = g;
        }
        __syncthreads();   // As safe to reuse for GEMM staging
    }

    // ---------------- expert L1 GEMM (byte-identical to verified R6) ------
    const int e = bz;
    const ushort* Ae = A;
    const ushort* We = Wt + (size_t)e * (size_t)EH1_ * IN_;
    const float* BiasE = Bias + (size_t)e * EH1_;
    ushort* Ce = C + (size_t)e * (size_t)B_ * EH1_;

    const int m0 = by * 128;
    const int n0 = bx * 128;
    const int wave = t >> 6;
    const int lane = t & 63;

    const int q0 = wave * 2, q1 = q0 + 1;
    const int sr0 = q0 * 16 + (lane >> 2);
    const int sr1 = sr0 + 16;
    const int sw  = ((lane & 3) ^ ((sr0 >> 1) & 3)) * 8;

    const int l32  = lane & 31;
    const int ksel = lane >> 5;
    const int rw = (wave & 1) * 64;
    const int cw = (wave >> 1) * 64;

    int rowA[2], rowB[2], swzA[2], swzB[2];
    #pragma unroll
    for (int i = 0; i < 2; ++i) {
        rowA[i] = rw + 32 * i + l32;  swzA[i] = (rowA[i] >> 1) & 3;
        rowB[i] = cw + 32 * i + l32;  swzB[i] = (rowB[i] >> 1) & 3;
    }

    f32x16 acc[2][2] = {};

    for (int k0 = 0; k0 < IN_; k0 += GBK) {
        GLOBAL_LDS16(Ae + (size_t)(m0 + sr0) * IN_ + k0 + sw, As + q0 * 512);
        GLOBAL_LDS16(Ae + (size_t)(m0 + sr1) * IN_ + k0 + sw, As + q1 * 512);
        GLOBAL_LDS16(We + (size_t)(n0 + sr0) * IN_ + k0 + sw, Bs + q0 * 512);
        GLOBAL_LDS16(We + (size_t)(n0 + sr1) * IN_ + k0 + sw, Bs + q1 * 512);
        __syncthreads();

        #pragma unroll
        for (int h = 0; h < 2; ++h) {
            const int cb = h * 2 + ksel;
            s16x8 af[2], bf[2];
            #pragma unroll
            for (int i = 0; i < 2; ++i)
                af[i] = *(const s16x8*)&As[rowA[i] * GBK + ((cb ^ swzA[i]) * 8)];
            #pragma unroll
            for (int j = 0; j < 2; ++j)
                bf[j] = *(const s16x8*)&Bs[rowB[j] * GBK + ((cb ^ swzB[j]) * 8)];
            #pragma unroll
            for (int i = 0; i < 2; ++i)
                #pragma unroll
                for (int j = 0; j < 2; ++j)
                    acc[i][j] = __builtin_amdgcn_mfma_f32_32x32x16_bf16(
                        af[i], bf[j], acc[i][j], 0, 0, 0);
        }
        __syncthreads();
    }

    float bi[2];
    #pragma unroll
    for (int j = 0; j < 2; ++j) bi[j] = BiasE[n0 + cw + 32 * j + l32];

    #pragma unroll
    for (int i = 0; i < 2; ++i) {
        #pragma unroll
        for (int reg = 0; reg < 16; ++reg) {
            int rowin = (reg & 3) + 8 * (reg >> 2) + 4 * ksel;
            ushort* crow = Ce + (size_t)(m0 + rw + 32 * i + rowin) * EH1_;
            #pragma unroll
            for (int j = 0; j < 2; ++j) {
                float v = fmaxf(acc[i][j][reg] + bi[j], 0.f);
                crow[n0 + cw + 32 * j + l32] = f2bf(v);
            }
        }
    }
}

#define GYL (E_ + 3)   // 6 l2eo expert slices + 3 gate-table slices

// ---------------------------------------------------------------------------
// Fused expert L2+L3 (verified path) for y<6; gate tiles (dense table) for
// y>=6. R6-verified merged form (R10's split cost exactly one launch, +4us).
// ---------------------------------------------------------------------------
__global__ __launch_bounds__(256) void k_l2eog(
        const ushort* __restrict__ h1, const ushort* __restrict__ W2t,
        const float* __restrict__ Eb2, const float* __restrict__ Ew3,
        const float* __restrict__ Eb3, float* __restrict__ eo,
        const ushort* __restrict__ xb, const ushort* __restrict__ Gw1t,
        const float* __restrict__ Gb1, const float* __restrict__ Gw2,
        const float* __restrict__ Gb2, const int* __restrict__ perm,
        const int* __restrict__ histG, const int* __restrict__ gbaseG,
        const int* __restrict__ gtab, const int* __restrict__ ngt,
        float* __restrict__ gate) {
    __shared__ __attribute__((aligned(16))) ushort smem[17408 + 16 * H2P];

    const int t = threadIdx.x;
    const int wave = t >> 6;
    const int lane = t & 63;
    const int quad = lane >> 4;
    const int l16  = lane & 15;
    const int l32  = lane & 31;
    const int ksel = lane >> 5;

    if (blockIdx.y < E_) {
        // ================= L2+L3 branch (verified R8 path) ================
        ushort* As = smem;            // 128*32 elems
        ushort* Bs = smem + 4096;     // 128*32 elems

        const int e = blockIdx.y;
        const ushort* Ae = h1 + (size_t)e * B_ * EH1_;
        const ushort* We = W2t + (size_t)e * EH2_ * EH1_;

        const int m0 = blockIdx.x * 128;

        const int q0 = wave * 2, q1 = q0 + 1;
        const int sr0 = q0 * 16 + (lane >> 2);
        const int sr1 = sr0 + 16;
        const int sw  = ((lane & 3) ^ ((sr0 >> 1) & 3)) * 8;

        const int rw = (wave & 1) * 64;
        const int cw = (wave >> 1) * 64;

        int rowA[2], rowB[2], swzA[2], swzB[2];
        #pragma unroll
        for (int i = 0; i < 2; ++i) {
            rowA[i] = rw + 32 * i + l32;  swzA[i] = (rowA[i] >> 1) & 3;
            rowB[i] = cw + 32 * i + l32;  swzB[i] = (rowB[i] >> 1) & 3;
        }

        f32x16 acc[2][2] = {};

        for (int k0 = 0; k0 < EH1_; k0 += GBK) {
            GLOBAL_LDS16(Ae + (size_t)(m0 + sr0) * EH1_ + k0 + sw, As + q0 * 512);
            GLOBAL_LDS16(Ae + (size_t)(m0 + sr1) * EH1_ + k0 + sw, As + q1 * 512);
            GLOBAL_LDS16(We + (size_t)sr0 * EH1_ + k0 + sw, Bs + q0 * 512);
            GLOBAL_LDS16(We + (size_t)sr1 * EH1_ + k0 + sw, Bs + q1 * 512);
            __syncthreads();

            #pragma unroll
            for (int h = 0; h < 2; ++h) {
                const int cb = h * 2 + ksel;
                s16x8 af[2], bf[2];
                #pragma unroll
                for (int i = 0; i < 2; ++i)
                    af[i] = *(const s16x8*)&As[rowA[i] * GBK + ((cb ^ swzA[i]) * 8)];
                #pragma unroll
                for (int j = 0; j < 2; ++j)
                    bf[j] = *(const s16x8*)&Bs[rowB[j] * GBK + ((cb ^ swzB[j]) * 8)];
                #pragma unroll
                for (int i = 0; i < 2; ++i)
                    #pragma unroll
                    for (int j = 0; j < 2; ++j)
                        acc[i][j] = __builtin_amdgcn_mfma_f32_32x32x16_bf16(
                            af[i], bf[j], acc[i][j], 0, 0, 0);
            }
            __syncthreads();
        }

        // epilogue: h2 tile (bias+relu, bf16) -> LDS, 32x32 C/D scatter
        ushort* h2L = smem;             // [128][H2P]
        ushort* E3t = smem + 128 * H2P; // [16][H2P]

        float bi[2];
        #pragma unroll
        for (int j = 0; j < 2; ++j) bi[j] = Eb2[e * EH2_ + cw + 32 * j + l32];

        #pragma unroll
        for (int i = 0; i < 2; ++i)
            #pragma unroll
            for (int reg = 0; reg < 16; ++reg) {
                int rowin = (reg & 3) + 8 * (reg >> 2) + 4 * ksel;
                int row = rw + 32 * i + rowin;
                #pragma unroll
                for (int j = 0; j < 2; ++j)
                    h2L[row * H2P + cw + 32 * j + l32] =
                        f2bf(fmaxf(acc[i][j][reg] + bi[j], 0.f));
            }

        for (int i = t; i < 16 * 128; i += 256) {
            int col = i >> 7, k = i & 127;
            float v = (col < EO_) ? Ew3[(size_t)e * EH2_ * EO_ + k * EO_ + col] : 0.f;
            E3t[col * H2P + k] = f2bf(v);
        }
        __syncthreads();

        #pragma unroll
        for (int gi = 0; gi < 2; ++gi) {
            int g = wave * 2 + gi;
            f32x4 acc2 = {};
            #pragma unroll
            for (int kc = 0; kc < 4; ++kc) {
                s16x8 a = *(const s16x8*)&h2L[(g * 16 + l16) * H2P + kc * 32 + quad * 8];
                s16x8 b = *(const s16x8*)&E3t[l16 * H2P + kc * 32 + quad * 8];
                acc2 = __builtin_amdgcn_mfma_f32_16x16x32_bf16(a, b, acc2, 0, 0, 0);
            }
            if (l16 < EO_) {
                float b3 = Eb3[e * EO_ + l16];
                #pragma unroll
                for (int r = 0; r < 4; ++r) {
                    int row = m0 + g * 16 + quad * 4 + r;
                    eo[(size_t)row * (E_ * EO_) + e * EO_ + l16] = acc2[r] + b3;
                }
            }
        }
        return;
    }

    // ===================== GATE branch (dense tile table) =================
    {
        const int gidx = (blockIdx.y - E_) * gridDim.x + blockIdx.x;
        if (gidx >= ngt[0]) return;
        const int entry = gtab[gidx];
        const int d     = entry >> 16;
        const int start = (entry & 0xffff) * 64;
        const int base  = gbaseG[d];
        const int cnt   = histG[d];

        // carve gate LDS out of smem (byte offsets; total smem = 39168 B)
        ushort* gAs  = smem;                                   // 4096 B @0
        ushort* gBs  = smem + 2048;                            // 4096 B @4096
        int*    ridx = (int*)(smem + 4096);                    // 256 B  @8192
        float (*gh)[GH_ + 1] = (float(*)[GH_ + 1])(smem + 4224);  // 16640 B @8448
        float*  w2s  = (float*)(smem + 12544);                 // 1536 B @25088
        float*  b2s  = (float*)(smem + 13312);                 // 24 B   @26624
        float (*lg)[E_] = (float(*)[E_])(smem + 13324);        // 1536 B @26648

        const int qsw = (quad ^ ((l16 >> 1) & 3)) * 8;

        if (t < 64) {
            int p = start + t;
            ridx[t] = (p < cnt) ? perm[base + p] : perm[base];  // clamp OOB
        }
        for (int i = t; i < GH_ * E_; i += 256) w2s[i] = Gw2[(size_t)d * GH_ * E_ + i];
        if (t < E_) b2s[t] = Gb2[d * E_ + t];
        __syncthreads();

        const int srow = t >> 2;
        const int sw   = ((t & 3) ^ ((srow >> 1) & 3)) * 8;
        const int myRow = ridx[srow];
        const ushort* aRow = xb + (size_t)myRow * IN_ + sw;
        const ushort* bRow = Gw1t + (size_t)d * GH_ * IN_ + (size_t)srow * IN_ + sw;

        f32x4 acc[4] = {};
        for (int k0 = 0; k0 < IN_; k0 += 32) {
            GLOBAL_LDS16(aRow + k0, gAs + wave * 512);
            GLOBAL_LDS16(bRow + k0, gBs + wave * 512);
            __syncthreads();

            s16x8 bf = *(const s16x8*)&gBs[(wave * 16 + l16) * 32 + qsw];
            #pragma unroll
            for (int i = 0; i < 4; ++i) {
                s16x8 af = *(const s16x8*)&gAs[(16 * i + l16) * 32 + qsw];
                acc[i] = __builtin_amdgcn_mfma_f32_16x16x32_bf16(af, bf, acc[i], 0, 0, 0);
            }
            __syncthreads();
        }

        const int hcol = wave * 16 + l16;
        float hb = Gb1[d * GH_ + hcol];
        #pragma unroll
        for (int i = 0; i < 4; ++i)
            #pragma unroll
            for (int r = 0; r < 4; ++r)
                gh[16 * i + quad * 4 + r][hcol] = fmaxf(acc[i][r] + hb, 0.f);
        __syncthreads();

        for (int p = t; p < 64 * E_; p += 256) {
            int row = p / E_, e = p - row * E_;
            float s = b2s[e];
            #pragma unroll 8
            for (int h = 0; h < GH_; ++h) s += gh[row][h] * w2s[h * E_ + e];
            lg[row][e] = s;
        }
        __syncthreads();

        if (t < 64 && start + t < cnt) {
            int b = ridx[t];
            float mx = lg[t][0];
            #pragma unroll
            for (int e = 1; e < E_; ++e) mx = fmaxf(mx, lg[t][e]);
            float ex[E_], sum = 0.f;
            #pragma unroll
            for (int e = 0; e < E_; ++e) { ex[e] = expf(lg[t][e] - mx); sum += ex[e]; }
            float inv = 1.f / sum;
            #pragma unroll
            for (int e = 0; e < E_; ++e) gate[(size_t)b * E_ + e] = ex[e] * inv;
        }
    }
}

// ---------------------------------------------------------------------------
// Final: MMoE combine + avg + tower, one wave per sample
// ---------------------------------------------------------------------------
__global__ __launch_bounds__(256) void k_final(
        const float* __restrict__ eo, const float* __restrict__ gate,
        const int* __restrict__ dom,
        const float* __restrict__ Tw1, const float* __restrict__ Tb1,
        const float* __restrict__ Tw2, const float* __restrict__ Tb2,
        float* __restrict__ out) {
    const int wave = threadIdx.x >> 6;
    const int lane = threadIdx.x & 63;
    const int b = blockIdx.x * 4 + wave;
    const int d = dom[b];

    const float* eob = eo + (size_t)b * (E_ * EO_);
    float g[E_];
    #pragma unroll
    for (int e = 0; e < E_; ++e) g[e] = gate[(size_t)b * E_ + e];

    float mmoe[EO_], avg[EO_];
    #pragma unroll
    for (int o = 0; o < EO_; ++o) {
        float m = 0.f, a = 0.f;
        #pragma unroll
        for (int e = 0; e < E_; ++e) {
            float v = eob[e * EO_ + o];
            m += g[e] * v;
            a += v;
        }
        mmoe[o] = m;
        avg[o] = a * (1.0f / E_);
    }

    float acc = Tb1[d * TH_ + lane];
    #pragma unroll
    for (int o = 0; o < EO_; ++o)
        acc += mmoe[o] * Tw1[(size_t)d * EO_ * TH_ + o * TH_ + lane];
    acc = fmaxf(acc, 0.f);

    float s = acc * Tw2[d * TH_ + lane];
    #pragma unroll
    for (int off = 32; off >= 1; off >>= 1) s += __shfl_xor(s, off, 64);

    if (lane == 0)
        out[b] = 1.f / (1.f + expf(-(s + Tb2[d])));
    if (lane < EO_) {
        out[B_ + (size_t)b * EO_ + lane] = avg[lane];
        out[B_ + (size_t)B_ * EO_ + (size_t)b * EO_ + lane] = mmoe[lane];
    }
}

// ---------------------------------------------------------------------------
extern "C" void kernel_launch(void* const* d_in, const int* in_sizes, int n_in,
                              void* d_out, int out_size, void* d_ws, size_t ws_size,
                              hipStream_t stream) {
    const float* x   = (const float*)d_in[0];
    const int*   dom = (const int*)d_in[1];
    const float* Ew1 = (const float*)d_in[2];
    const float* Eb1 = (const float*)d_in[3];
    const float* Ew2 = (const float*)d_in[4];
    const float* Eb2 = (const float*)d_in[5];
    const float* Ew3 = (const float*)d_in[6];
    const float* Eb3 = (const float*)d_in[7];
    const float* Gw1 = (const float*)d_in[8];
    const float* Gb1 = (const float*)d_in[9];
    const float* Gw2 = (const float*)d_in[10];
    const float* Gb2 = (const float*)d_in[11];
    const float* Tw1 = (const float*)d_in[12];
    const float* Tb1 = (const float*)d_in[13];
    const float* Tw2 = (const float*)d_in[14];
    const float* Tb2 = (const float*)d_in[15];
    float* out = (float*)d_out;

    char* ws = (char*)d_ws;
    size_t off = 0;
    auto take = [&](size_t bytes) -> char* {
        char* p = ws + off;
        off = (off + bytes + 255) & ~(size_t)255;
        return p;
    };
    int*    cnts    = (int*)take((size_t)NCHUNK * D_ * 4);
    int*    histG   = (int*)take(D_ * 4);
    int*    gbaseG  = (int*)take(D_ * 4);
    int*    gtab    = (int*)take(512 * 4);
    int*    ngt     = (int*)take(4);
    int*    perm    = (int*)take(B_ * 4);
    float*  gateBuf = (float*)take((size_t)B_ * E_ * 4);
    float*  eoBuf   = (float*)take((size_t)B_ * E_ * EO_ * 4);
    ushort* xb      = (ushort*)take((size_t)B_ * IN_ * 2);
    ushort* W1t     = (ushort*)take((size_t)E_ * IN_ * EH1_ * 2);
    ushort* W2t     = (ushort*)take((size_t)E_ * EH1_ * EH2_ * 2);
    ushort* G1t     = (ushort*)take((size_t)D_ * IN_ * GH_ * 2);
    ushort* h1      = (ushort*)take((size_t)E_ * B_ * EH1_ * 2);

    // 1) conversions + 64x64-tile transposes + per-chunk counts
    k_prep<<<dim3(PREP_BLKS), dim3(256), 0, stream>>>(
        x, xb, Ew1, W1t, Ew2, W2t, Gw1, G1t, dom, cnts);

    // 2) L1 GEMM (XCD-remapped); scatter prologue on 64 resident blocks
    k_gemm<<<dim3(EH1_ / 128, B_ / 128, E_), dim3(256), 0, stream>>>(
        xb, W1t, Eb1, h1, dom, cnts, perm, gbaseG, histG, gtab, ngt);

    // 3) fused L2+L3 (y<6) + gates (y>=6, dense table) — R6-verified merge
    k_l2eog<<<dim3(B_ / 128, GYL), dim3(256), 0, stream>>>(
        h1, W2t, Eb2, Ew3, Eb3, eoBuf,
        xb, G1t, Gb1, Gw2, Gb2, perm, histG, gbaseG, gtab, ngt, gateBuf);

    // 4) combine + towers + outputs
    k_final<<<dim3(B_ / 4), dim3(256), 0, stream>>>(
        eoBuf, gateBuf, dom, Tw1, Tb1, Tw2, Tb2, out);
}

// Round 12
// 237.914 us; speedup vs baseline: 1.1454x; 1.0102x over previous
//
#include <hip/hip_runtime.h>
#include <hip/hip_bf16.h>
#include <math.h>

// Problem constants (HC2MMoE)
#define B_    16384
#define IN_   1024
#define E_    6
#define D_    20
#define EH1_  256
#define EH2_  128
#define EO_   10
#define GH_   64
#define TH_   64

typedef short  s16x8  __attribute__((ext_vector_type(8)));   // 8 bf16 = 4 VGPRs
typedef float  f32x4  __attribute__((ext_vector_type(4)));
typedef float  f32x16 __attribute__((ext_vector_type(16)));

__device__ inline ushort f2bf(float f) {   // RNE fp32 -> bf16 bits
    union { float f; uint32_t u; } v; v.f = f;
    return (ushort)((v.u + 0x7fffu + ((v.u >> 16) & 1u)) >> 16);
}

#define GLOBAL_LDS16(g, l)                                                     \
    __builtin_amdgcn_global_load_lds(                                          \
        (const __attribute__((address_space(1))) void*)(g),                    \
        (__attribute__((address_space(3))) void*)(l), 16, 0, 0)

#define NCHUNK (B_ / 256)   // 64

// ---------------------------------------------------------------------------
// Prep (R11-verified): x-convert + 64x64-tile weight transposes + counts.
// ---------------------------------------------------------------------------
#define CVT_BLKS  2048
#define CVT_ITERS (B_ * IN_ / 4 / 256 / CVT_BLKS)            // 8
#define WT1_T64 (E_ * (EH1_ / 64) * (IN_ / 64))              // 384
#define WT2_T64 (E_ * (EH2_ / 64) * (EH1_ / 64))             // 48
#define WTG_T64 (D_ * (GH_ / 64) * (IN_ / 64))               // 320
#define PREP_BLKS (CVT_BLKS + WT1_T64 + WT2_T64 + WTG_T64 + NCHUNK)

__global__ __launch_bounds__(256) void k_prep(
        const float* __restrict__ x, ushort* __restrict__ xb,
        const float* __restrict__ Ew1, ushort* __restrict__ W1t,
        const float* __restrict__ Ew2, ushort* __restrict__ W2t,
        const float* __restrict__ Gw1, ushort* __restrict__ G1t,
        const int* __restrict__ dom, int* __restrict__ cnts) {
    __shared__ float tile[64][65];
    __shared__ int hcnt[D_];
    int bid = blockIdx.x;
    const int t = threadIdx.x;

    if (bid < CVT_BLKS) {
        int i = bid * 256 + t;
        #pragma unroll
        for (int it = 0; it < CVT_ITERS; ++it, i += CVT_BLKS * 256) {
            float4 v = ((const float4*)x)[i];
            ushort4 o;
            o.x = f2bf(v.x); o.y = f2bf(v.y); o.z = f2bf(v.z); o.w = f2bf(v.w);
            ((ushort4*)xb)[i] = o;
        }
        return;
    }
    bid -= CVT_BLKS;

    const float* W; ushort* Wt; int K, N, z, ky, nx;
    if (bid < WT1_T64) {
        W = Ew1; Wt = W1t; K = IN_; N = EH1_;
        z = bid / (4 * 16); int r = bid % (4 * 16); ky = r / 4; nx = r % 4;
    } else if (bid < WT1_T64 + WT2_T64) {
        bid -= WT1_T64;
        W = Ew2; Wt = W2t; K = EH1_; N = EH2_;
        z = bid / (2 * 4); int r = bid % (2 * 4); ky = r / 2; nx = r % 2;
    } else if (bid < WT1_T64 + WT2_T64 + WTG_T64) {
        bid -= WT1_T64 + WT2_T64;
        W = Gw1; Wt = G1t; K = IN_; N = GH_;
        z = bid / 16; ky = bid % 16; nx = 0;
    } else {
        // per-chunk count blocks: 256 samples each, LDS counts -> direct write
        int c = bid - (WT1_T64 + WT2_T64 + WTG_T64);
        if (t < D_) hcnt[t] = 0;
        __syncthreads();
        atomicAdd(&hcnt[dom[c * 256 + t]], 1);
        __syncthreads();
        if (t < D_) cnts[c * D_ + t] = hcnt[t];
        return;
    }
    const int n0 = nx * 64, k0 = ky * 64;
    const float* We = W + (size_t)z * K * N;
    ushort* Wte = Wt + (size_t)z * K * N;
    const int lx = t & 63, ly = t >> 6;          // ly: 0..3, 16 rows each
    #pragma unroll
    for (int r = 0; r < 16; ++r)
        tile[ly * 16 + r][lx] = We[(size_t)(k0 + ly * 16 + r) * N + n0 + lx];
    __syncthreads();
    #pragma unroll
    for (int r = 0; r < 16; ++r)
        Wte[(size_t)(n0 + ly * 16 + r) * K + k0 + lx] =
            f2bf(tile[lx][ly * 16 + r]);
}

#define GBK 32
#define H2P 136

// ---------------------------------------------------------------------------
// L1 GEMM (R12): verified 128x128/BK=32 fragment scheme + XCD remap (R11,
// FETCH 72->45MB) + NEW single-barrier double-buffered K-loop (T3 minimum
// 2-phase): issue next window's 4 global_load_lds BEFORE computing current,
// ONE __syncthreads per window (its mandatory vmcnt drain now waits only the
// residual load latency). Barriers/block 64 -> 32. LDS 32KB -> 5 blocks/CU
// (1536-block grid backfills; per-CU work unchanged at 6 blocks).
// Scatter prologue on 64 remapped blocks (R6-verified).
// ---------------------------------------------------------------------------
__global__ __launch_bounds__(256) void k_gemm(
        const ushort* __restrict__ A, const ushort* __restrict__ Wt,
        const float* __restrict__ Bias, ushort* __restrict__ C,
        const int* __restrict__ dom, const int* __restrict__ cnts,
        int* __restrict__ perm, int* __restrict__ gbaseG,
        int* __restrict__ histG, int* __restrict__ gtab,
        int* __restrict__ ngt) {
    __shared__ __attribute__((aligned(16))) ushort As[2][128 * GBK];  // 16 KB
    __shared__ __attribute__((aligned(16))) ushort Bs[2][128 * GBK];  // 16 KB

    const int t = threadIdx.x;

    // XCD remap (grid is (2,128,6); HW dispatch order: x fastest)
    const int lin = blockIdx.x + 2 * blockIdx.y + 256 * blockIdx.z;
    const int q  = lin & 7;
    const int rr = lin >> 3;                 // 0..191
    const int by = q * 16 + (rr & 15);
    const int bx = (rr >> 4) & 1;
    const int bz = rr >> 5;                  // 0..5

    if (bz == 0 && bx == 0 && by < NCHUNK) {
        // ---------- scatter prologue (LDS aliases As; done before staging) --
        int* cl    = (int*)As;              // [NCHUNK*D_] = 1280 ints (5120B)
        int* tot   = cl + NCHUNK * D_;      // [D_]
        int* lbase = tot + D_;              // [D_]
        int* lcnt  = lbase + D_;            // [D_]
        const int c = by;

        for (int i = t; i < NCHUNK * D_; i += 256) cl[i] = cnts[i];
        __syncthreads();
        if (t < D_) {
            int before = 0, total = 0;
            #pragma unroll 8
            for (int cc = 0; cc < NCHUNK; ++cc) {
                int v = cl[cc * D_ + t];
                if (cc < c) before += v;
                total += v;
            }
            tot[t] = total; lbase[t] = before; lcnt[t] = 0;
        }
        __syncthreads();
        if (t < D_) {
            int gb = 0;
            #pragma unroll
            for (int d2 = 0; d2 < D_; ++d2) if (d2 < t) gb += tot[d2];
            lbase[t] += gb;
            if (c == 0) { gbaseG[t] = gb; histG[t] = tot[t]; }
        }
        __syncthreads();
        if (c == 0 && t < D_) {
            // parallel gate-table build: thread t owns domain t's entries
            int off = 0, nt = (tot[t] + 63) >> 6;
            #pragma unroll
            for (int d2 = 0; d2 < D_; ++d2)
                if (d2 < t) off += (tot[d2] + 63) >> 6;
            for (int tt = 0; tt < nt; ++tt) gtab[off + tt] = (t << 16) | tt;
            if (t == D_ - 1) ngt[0] = off + nt;
        }
        {
            const int g = c * 256 + t;
            const int d = dom[g];
            int r = atomicAdd(&lcnt[d], 1);     // LDS-only rank within chunk
            perm[lbase[d] + r] = g;
        }
        __syncthreads();   // As safe to reuse for GEMM staging
    }

    // ---------------- expert L1 GEMM ----------------
    const int e = bz;
    const ushort* Ae = A;
    const ushort* We = Wt + (size_t)e * (size_t)EH1_ * IN_;
    const float* BiasE = Bias + (size_t)e * EH1_;
    ushort* Ce = C + (size_t)e * (size_t)B_ * EH1_;

    const int m0 = by * 128;
    const int n0 = bx * 128;
    const int wave = t >> 6;
    const int lane = t & 63;

    const int q0 = wave * 2, q1 = q0 + 1;
    const int sr0 = q0 * 16 + (lane >> 2);
    const int sr1 = sr0 + 16;
    const int sw  = ((lane & 3) ^ ((sr0 >> 1) & 3)) * 8;

    const int l32  = lane & 31;
    const int ksel = lane >> 5;
    const int rw = (wave & 1) * 64;
    const int cw = (wave >> 1) * 64;

    int rowA[2], rowB[2], swzA[2], swzB[2];
    #pragma unroll
    for (int i = 0; i < 2; ++i) {
        rowA[i] = rw + 32 * i + l32;  swzA[i] = (rowA[i] >> 1) & 3;
        rowB[i] = cw + 32 * i + l32;  swzB[i] = (rowB[i] >> 1) & 3;
    }

    const ushort* aS0 = Ae + (size_t)(m0 + sr0) * IN_ + sw;
    const ushort* aS1 = Ae + (size_t)(m0 + sr1) * IN_ + sw;
    const ushort* bS0 = We + (size_t)(n0 + sr0) * IN_ + sw;
    const ushort* bS1 = We + (size_t)(n0 + sr1) * IN_ + sw;

    f32x16 acc[2][2] = {};

#define STAGE_W(buf, kk)                                                       \
    do {                                                                       \
        GLOBAL_LDS16(aS0 + (kk), &As[buf][q0 * 512]);                          \
        GLOBAL_LDS16(aS1 + (kk), &As[buf][q1 * 512]);                          \
        GLOBAL_LDS16(bS0 + (kk), &Bs[buf][q0 * 512]);                          \
        GLOBAL_LDS16(bS1 + (kk), &Bs[buf][q1 * 512]);                          \
    } while (0)

#define COMPUTE_W(buf)                                                         \
    do {                                                                       \
        _Pragma("unroll")                                                      \
        for (int h = 0; h < 2; ++h) {                                          \
            const int cb = h * 2 + ksel;                                       \
            s16x8 af[2], bf[2];                                                \
            _Pragma("unroll")                                                  \
            for (int i = 0; i < 2; ++i)                                        \
                af[i] = *(const s16x8*)&As[buf][rowA[i] * GBK +                 \
                                               ((cb ^ swzA[i]) * 8)];          \
            _Pragma("unroll")                                                  \
            for (int j = 0; j < 2; ++j)                                        \
                bf[j] = *(const s16x8*)&Bs[buf][rowB[j] * GBK +                 \
                                               ((cb ^ swzB[j]) * 8)];          \
            _Pragma("unroll")                                                  \
            for (int i = 0; i < 2; ++i)                                        \
                _Pragma("unroll")                                              \
                for (int j = 0; j < 2; ++j)                                    \
                    acc[i][j] = __builtin_amdgcn_mfma_f32_32x32x16_bf16(       \
                        af[i], bf[j], acc[i][j], 0, 0, 0);                     \
        }                                                                      \
    } while (0)

    // prologue: stage window 0 into buffer 0
    STAGE_W(0, 0);
    __syncthreads();

    #pragma unroll 1
    for (int w = 0; w < IN_ / GBK; w += 2) {
        STAGE_W(1, (w + 1) * GBK);         // prefetch next window (w+1 <= 31)
        COMPUTE_W(0);
        __syncthreads();                   // drains buf1 loads + buf0 reads
        if (w + 2 < IN_ / GBK) STAGE_W(0, (w + 2) * GBK);
        COMPUTE_W(1);
        __syncthreads();                   // drains buf0 loads + buf1 reads
    }
#undef STAGE_W
#undef COMPUTE_W

    float bi[2];
    #pragma unroll
    for (int j = 0; j < 2; ++j) bi[j] = BiasE[n0 + cw + 32 * j + l32];

    #pragma unroll
    for (int i = 0; i < 2; ++i) {
        #pragma unroll
        for (int reg = 0; reg < 16; ++reg) {
            int rowin = (reg & 3) + 8 * (reg >> 2) + 4 * ksel;
            ushort* crow = Ce + (size_t)(m0 + rw + 32 * i + rowin) * EH1_;
            #pragma unroll
            for (int j = 0; j < 2; ++j) {
                float v = fmaxf(acc[i][j][reg] + bi[j], 0.f);
                crow[n0 + cw + 32 * j + l32] = f2bf(v);
            }
        }
    }
}

#define GYL (E_ + 3)   // 6 l2eo expert slices + 3 gate-table slices

// ---------------------------------------------------------------------------
// Fused expert L2+L3 (verified path) for y<6; gate tiles (dense table) for
// y>=6. R6-verified merged form.
// ---------------------------------------------------------------------------
__global__ __launch_bounds__(256) void k_l2eog(
        const ushort* __restrict__ h1, const ushort* __restrict__ W2t,
        const float* __restrict__ Eb2, const float* __restrict__ Ew3,
        const float* __restrict__ Eb3, float* __restrict__ eo,
        const ushort* __restrict__ xb, const ushort* __restrict__ Gw1t,
        const float* __restrict__ Gb1, const float* __restrict__ Gw2,
        const float* __restrict__ Gb2, const int* __restrict__ perm,
        const int* __restrict__ histG, const int* __restrict__ gbaseG,
        const int* __restrict__ gtab, const int* __restrict__ ngt,
        float* __restrict__ gate) {
    __shared__ __attribute__((aligned(16))) ushort smem[17408 + 16 * H2P];

    const int t = threadIdx.x;
    const int wave = t >> 6;
    const int lane = t & 63;
    const int quad = lane >> 4;
    const int l16  = lane & 15;
    const int l32  = lane & 31;
    const int ksel = lane >> 5;

    if (blockIdx.y < E_) {
        // ================= L2+L3 branch (verified R8 path) ================
        ushort* As = smem;            // 128*32 elems
        ushort* Bs = smem + 4096;     // 128*32 elems

        const int e = blockIdx.y;
        const ushort* Ae = h1 + (size_t)e * B_ * EH1_;
        const ushort* We = W2t + (size_t)e * EH2_ * EH1_;

        const int m0 = blockIdx.x * 128;

        const int q0 = wave * 2, q1 = q0 + 1;
        const int sr0 = q0 * 16 + (lane >> 2);
        const int sr1 = sr0 + 16;
        const int sw  = ((lane & 3) ^ ((sr0 >> 1) & 3)) * 8;

        const int rw = (wave & 1) * 64;
        const int cw = (wave >> 1) * 64;

        int rowA[2], rowB[2], swzA[2], swzB[2];
        #pragma unroll
        for (int i = 0; i < 2; ++i) {
            rowA[i] = rw + 32 * i + l32;  swzA[i] = (rowA[i] >> 1) & 3;
            rowB[i] = cw + 32 * i + l32;  swzB[i] = (rowB[i] >> 1) & 3;
        }

        f32x16 acc[2][2] = {};

        for (int k0 = 0; k0 < EH1_; k0 += GBK) {
            GLOBAL_LDS16(Ae + (size_t)(m0 + sr0) * EH1_ + k0 + sw, As + q0 * 512);
            GLOBAL_LDS16(Ae + (size_t)(m0 + sr1) * EH1_ + k0 + sw, As + q1 * 512);
            GLOBAL_LDS16(We + (size_t)sr0 * EH1_ + k0 + sw, Bs + q0 * 512);
            GLOBAL_LDS16(We + (size_t)sr1 * EH1_ + k0 + sw, Bs + q1 * 512);
            __syncthreads();

            #pragma unroll
            for (int h = 0; h < 2; ++h) {
                const int cb = h * 2 + ksel;
                s16x8 af[2], bf[2];
                #pragma unroll
                for (int i = 0; i < 2; ++i)
                    af[i] = *(const s16x8*)&As[rowA[i] * GBK + ((cb ^ swzA[i]) * 8)];
                #pragma unroll
                for (int j = 0; j < 2; ++j)
                    bf[j] = *(const s16x8*)&Bs[rowB[j] * GBK + ((cb ^ swzB[j]) * 8)];
                #pragma unroll
                for (int i = 0; i < 2; ++i)
                    #pragma unroll
                    for (int j = 0; j < 2; ++j)
                        acc[i][j] = __builtin_amdgcn_mfma_f32_32x32x16_bf16(
                            af[i], bf[j], acc[i][j], 0, 0, 0);
            }
            __syncthreads();
        }

        // epilogue: h2 tile (bias+relu, bf16) -> LDS, 32x32 C/D scatter
        ushort* h2L = smem;             // [128][H2P]
        ushort* E3t = smem + 128 * H2P; // [16][H2P]

        float bi[2];
        #pragma unroll
        for (int j = 0; j < 2; ++j) bi[j] = Eb2[e * EH2_ + cw + 32 * j + l32];

        #pragma unroll
        for (int i = 0; i < 2; ++i)
            #pragma unroll
            for (int reg = 0; reg < 16; ++reg) {
                int rowin = (reg & 3) + 8 * (reg >> 2) + 4 * ksel;
                int row = rw + 32 * i + rowin;
                #pragma unroll
                for (int j = 0; j < 2; ++j)
                    h2L[row * H2P + cw + 32 * j + l32] =
                        f2bf(fmaxf(acc[i][j][reg] + bi[j], 0.f));
            }

        for (int i = t; i < 16 * 128; i += 256) {
            int col = i >> 7, k = i & 127;
            float v = (col < EO_) ? Ew3[(size_t)e * EH2_ * EO_ + k * EO_ + col] : 0.f;
            E3t[col * H2P + k] = f2bf(v);
        }
        __syncthreads();

        #pragma unroll
        for (int gi = 0; gi < 2; ++gi) {
            int g = wave * 2 + gi;
            f32x4 acc2 = {};
            #pragma unroll
            for (int kc = 0; kc < 4; ++kc) {
                s16x8 a = *(const s16x8*)&h2L[(g * 16 + l16) * H2P + kc * 32 + quad * 8];
                s16x8 b = *(const s16x8*)&E3t[l16 * H2P + kc * 32 + quad * 8];
                acc2 = __builtin_amdgcn_mfma_f32_16x16x32_bf16(a, b, acc2, 0, 0, 0);
            }
            if (l16 < EO_) {
                float b3 = Eb3[e * EO_ + l16];
                #pragma unroll
                for (int r = 0; r < 4; ++r) {
                    int row = m0 + g * 16 + quad * 4 + r;
                    eo[(size_t)row * (E_ * EO_) + e * EO_ + l16] = acc2[r] + b3;
                }
            }
        }
        return;
    }

    // ===================== GATE branch (dense tile table) =================
    {
        const int gidx = (blockIdx.y - E_) * gridDim.x + blockIdx.x;
        if (gidx >= ngt[0]) return;
        const int entry = gtab[gidx];
        const int d     = entry >> 16;
        const int start = (entry & 0xffff) * 64;
        const int base  = gbaseG[d];
        const int cnt   = histG[d];

        // carve gate LDS out of smem (byte offsets; total smem = 39168 B)
        ushort* gAs  = smem;                                   // 4096 B @0
        ushort* gBs  = smem + 2048;                            // 4096 B @4096
        int*    ridx = (int*)(smem + 4096);                    // 256 B  @8192
        float (*gh)[GH_ + 1] = (float(*)[GH_ + 1])(smem + 4224);  // 16640 B @8448
        float*  w2s  = (float*)(smem + 12544);                 // 1536 B @25088
        float*  b2s  = (float*)(smem + 13312);                 // 24 B   @26624
        float (*lg)[E_] = (float(*)[E_])(smem + 13324);        // 1536 B @26648

        const int qsw = (quad ^ ((l16 >> 1) & 3)) * 8;

        if (t < 64) {
            int p = start + t;
            ridx[t] = (p < cnt) ? perm[base + p] : perm[base];  // clamp OOB
        }
        for (int i = t; i < GH_ * E_; i += 256) w2s[i] = Gw2[(size_t)d * GH_ * E_ + i];
        if (t < E_) b2s[t] = Gb2[d * E_ + t];
        __syncthreads();

        const int srow = t >> 2;
        const int sw   = ((t & 3) ^ ((srow >> 1) & 3)) * 8;
        const int myRow = ridx[srow];
        const ushort* aRow = xb + (size_t)myRow * IN_ + sw;
        const ushort* bRow = Gw1t + (size_t)d * GH_ * IN_ + (size_t)srow * IN_ + sw;

        f32x4 acc[4] = {};
        for (int k0 = 0; k0 < IN_; k0 += 32) {
            GLOBAL_LDS16(aRow + k0, gAs + wave * 512);
            GLOBAL_LDS16(bRow + k0, gBs + wave * 512);
            __syncthreads();

            s16x8 bf = *(const s16x8*)&gBs[(wave * 16 + l16) * 32 + qsw];
            #pragma unroll
            for (int i = 0; i < 4; ++i) {
                s16x8 af = *(const s16x8*)&gAs[(16 * i + l16) * 32 + qsw];
                acc[i] = __builtin_amdgcn_mfma_f32_16x16x32_bf16(af, bf, acc[i], 0, 0, 0);
            }
            __syncthreads();
        }

        const int hcol = wave * 16 + l16;
        float hb = Gb1[d * GH_ + hcol];
        #pragma unroll
        for (int i = 0; i < 4; ++i)
            #pragma unroll
            for (int r = 0; r < 4; ++r)
                gh[16 * i + quad * 4 + r][hcol] = fmaxf(acc[i][r] + hb, 0.f);
        __syncthreads();

        for (int p = t; p < 64 * E_; p += 256) {
            int row = p / E_, e = p - row * E_;
            float s = b2s[e];
            #pragma unroll 8
            for (int h = 0; h < GH_; ++h) s += gh[row][h] * w2s[h * E_ + e];
            lg[row][e] = s;
        }
        __syncthreads();

        if (t < 64 && start + t < cnt) {
            int b = ridx[t];
            float mx = lg[t][0];
            #pragma unroll
            for (int e = 1; e < E_; ++e) mx = fmaxf(mx, lg[t][e]);
            float ex[E_], sum = 0.f;
            #pragma unroll
            for (int e = 0; e < E_; ++e) { ex[e] = expf(lg[t][e] - mx); sum += ex[e]; }
            float inv = 1.f / sum;
            #pragma unroll
            for (int e = 0; e < E_; ++e) gate[(size_t)b * E_ + e] = ex[e] * inv;
        }
    }
}

// ---------------------------------------------------------------------------
// Final: MMoE combine + avg + tower, one wave per sample
// ---------------------------------------------------------------------------
__global__ __launch_bounds__(256) void k_final(
        const float* __restrict__ eo, const float* __restrict__ gate,
        const int* __restrict__ dom,
        const float* __restrict__ Tw1, const float* __restrict__ Tb1,
        const float* __restrict__ Tw2, const float* __restrict__ Tb2,
        float* __restrict__ out) {
    const int wave = threadIdx.x >> 6;
    const int lane = threadIdx.x & 63;
    const int b = blockIdx.x * 4 + wave;
    const int d = dom[b];

    const float* eob = eo + (size_t)b * (E_ * EO_);
    float g[E_];
    #pragma unroll
    for (int e = 0; e < E_; ++e) g[e] = gate[(size_t)b * E_ + e];

    float mmoe[EO_], avg[EO_];
    #pragma unroll
    for (int o = 0; o < EO_; ++o) {
        float m = 0.f, a = 0.f;
        #pragma unroll
        for (int e = 0; e < E_; ++e) {
            float v = eob[e * EO_ + o];
            m += g[e] * v;
            a += v;
        }
        mmoe[o] = m;
        avg[o] = a * (1.0f / E_);
    }

    float acc = Tb1[d * TH_ + lane];
    #pragma unroll
    for (int o = 0; o < EO_; ++o)
        acc += mmoe[o] * Tw1[(size_t)d * EO_ * TH_ + o * TH_ + lane];
    acc = fmaxf(acc, 0.f);

    float s = acc * Tw2[d * TH_ + lane];
    #pragma unroll
    for (int off = 32; off >= 1; off >>= 1) s += __shfl_xor(s, off, 64);

    if (lane == 0)
        out[b] = 1.f / (1.f + expf(-(s + Tb2[d])));
    if (lane < EO_) {
        out[B_ + (size_t)b * EO_ + lane] = avg[lane];
        out[B_ + (size_t)B_ * EO_ + (size_t)b * EO_ + lane] = mmoe[lane];
    }
}

// ---------------------------------------------------------------------------
extern "C" void kernel_launch(void* const* d_in, const int* in_sizes, int n_in,
                              void* d_out, int out_size, void* d_ws, size_t ws_size,
                              hipStream_t stream) {
    const float* x   = (const float*)d_in[0];
    const int*   dom = (const int*)d_in[1];
    const float* Ew1 = (const float*)d_in[2];
    const float* Eb1 = (const float*)d_in[3];
    const float* Ew2 = (const float*)d_in[4];
    const float* Eb2 = (const float*)d_in[5];
    const float* Ew3 = (const float*)d_in[6];
    const float* Eb3 = (const float*)d_in[7];
    const float* Gw1 = (const float*)d_in[8];
    const float* Gb1 = (const float*)d_in[9];
    const float* Gw2 = (const float*)d_in[10];
    const float* Gb2 = (const float*)d_in[11];
    const float* Tw1 = (const float*)d_in[12];
    const float* Tb1 = (const float*)d_in[13];
    const float* Tw2 = (const float*)d_in[14];
    const float* Tb2 = (const float*)d_in[15];
    float* out = (float*)d_out;

    char* ws = (char*)d_ws;
    size_t off = 0;
    auto take = [&](size_t bytes) -> char* {
        char* p = ws + off;
        off = (off + bytes + 255) & ~(size_t)255;
        return p;
    };
    int*    cnts    = (int*)take((size_t)NCHUNK * D_ * 4);
    int*    histG   = (int*)take(D_ * 4);
    int*    gbaseG  = (int*)take(D_ * 4);
    int*    gtab    = (int*)take(512 * 4);
    int*    ngt     = (int*)take(4);
    int*    perm    = (int*)take(B_ * 4);
    float*  gateBuf = (float*)take((size_t)B_ * E_ * 4);
    float*  eoBuf   = (float*)take((size_t)B_ * E_ * EO_ * 4);
    ushort* xb      = (ushort*)take((size_t)B_ * IN_ * 2);
    ushort* W1t     = (ushort*)take((size_t)E_ * IN_ * EH1_ * 2);
    ushort* W2t     = (ushort*)take((size_t)E_ * EH1_ * EH2_ * 2);
    ushort* G1t     = (ushort*)take((size_t)D_ * IN_ * GH_ * 2);
    ushort* h1      = (ushort*)take((size_t)E_ * B_ * EH1_ * 2);

    // 1) conversions + 64x64-tile transposes + per-chunk counts
    k_prep<<<dim3(PREP_BLKS), dim3(256), 0, stream>>>(
        x, xb, Ew1, W1t, Ew2, W2t, Gw1, G1t, dom, cnts);

    // 2) L1 GEMM (XCD-remapped, single-barrier dbuf); scatter prologue
    k_gemm<<<dim3(EH1_ / 128, B_ / 128, E_), dim3(256), 0, stream>>>(
        xb, W1t, Eb1, h1, dom, cnts, perm, gbaseG, histG, gtab, ngt);

    // 3) fused L2+L3 (y<6) + gates (y>=6, dense table) — R6-verified merge
    k_l2eog<<<dim3(B_ / 128, GYL), dim3(256), 0, stream>>>(
        h1, W2t, Eb2, Ew3, Eb3, eoBuf,
        xb, G1t, Gb1, Gw2, Gb2, perm, histG, gbaseG, gtab, ngt, gateBuf);

    // 4) combine + towers + outputs
    k_final<<<dim3(B_ / 4), dim3(256), 0, stream>>>(
        eoBuf, gateBuf, dom, Tw1, Tb1, Tw2, Tb2, out);
}